// Round 5
// baseline (402.483 us; speedup 1.0000x reference)
//
#include <hip/hip_runtime.h>

#define IN_F  32
#define HID_F 64
#define OUT_F 32

#define BKT_SHIFT 8            // 256 nodes per bucket
#define BKT_NODES 256
#define NSLICE    8            // XCD slices (blockIdx & 7)
#define GRID_PART 512          // blocks for count/append — MUST match between them

// ================= phase 1: per-(bucket,slice) exact counts =================
// cell = bucket*8 + slice, slice = blockIdx&7. Edge->block mapping must be
// identical to append_kernel (same grid/stride). LDS hist capped at 1024 buckets
// (n <= 262144; harness n = 100000 -> 391 buckets).
__global__ __launch_bounds__(256) void count_kernel(const int* __restrict__ dst,
                                                    int* __restrict__ cnt, int E, int nb)
{
    __shared__ int hist[1024];
    int tid = threadIdx.x;
    for (int i = tid; i < nb; i += 256) hist[i] = 0;
    __syncthreads();
    int s = blockIdx.x & (NSLICE - 1);
    for (int e = blockIdx.x * 256 + tid; e < E; e += GRID_PART * 256)
        atomicAdd(&hist[dst[e] >> BKT_SHIFT], 1);
    __syncthreads();
    for (int i = tid; i < nb; i += 256) {
        int c = hist[i];
        if (c) atomicAdd(&cnt[i * NSLICE + s], c);
    }
}

// ================= phase 2: scan cells -> cellstart, init cur =================
// nc = nb*8 <= 8192 (8 elems/thread). Also writes rowstart[n] = E.
__global__ __launch_bounds__(1024) void scancells_kernel(
    const int* __restrict__ cnt, int* __restrict__ cellstart, int* __restrict__ cur,
    int nc, int* __restrict__ rowstart, int n, int E)
{
    __shared__ int ts[1024];
    int tid = threadIdx.x;
    int base = tid * 8;
    int v[8]; int sum = 0;
    #pragma unroll
    for (int i = 0; i < 8; ++i) {
        int idx = base + i;
        v[i] = (idx < nc) ? cnt[idx] : 0;
        sum += v[i];
    }
    ts[tid] = sum;
    __syncthreads();
    for (int off = 1; off < 1024; off <<= 1) {
        int t = (tid >= off) ? ts[tid - off] : 0;
        __syncthreads();
        ts[tid] += t;
        __syncthreads();
    }
    int ex = ts[tid] - sum;           // exclusive prefix of this thread's chunk
    #pragma unroll
    for (int i = 0; i < 8; ++i) {
        int idx = base + i;
        if (idx < nc) { cellstart[idx] = ex; cur[idx] = ex; ex += v[i]; }
    }
    if (tid == 0) { cellstart[nc] = E; rowstart[n] = E; }
}

// ================= phase 3: sliced append of packed (src,dstLocal) =================
// pack = (src << 8) | (dst & 255)  — src < 2^24. Same-slice blocks land on the
// same XCD under round-robin dispatch -> append frontiers stay L2-local.
__global__ __launch_bounds__(256) void append_kernel(
    const int* __restrict__ src, const int* __restrict__ dst,
    int* __restrict__ cur, unsigned* __restrict__ pairs, int E)
{
    int s = blockIdx.x & (NSLICE - 1);
    for (int e = blockIdx.x * 256 + threadIdx.x; e < E; e += GRID_PART * 256) {
        int d = dst[e];
        int cell = (d >> BKT_SHIFT) * NSLICE + s;
        int pos = atomicAdd(&cur[cell], 1);
        pairs[pos] = ((unsigned)src[e] << BKT_SHIFT) | (unsigned)(d & (BKT_NODES - 1));
    }
}

// ================= phase 4: per-bucket place + rowstart + dinv =================
// One block per bucket. Bucket b's pairs live at [cellstart[b*8], cellstart[(b+1)*8])
// (contiguous, b-major cells) and its CSR window starts at cellstart[b*8].
__global__ __launch_bounds__(256) void place_kernel(
    const int* __restrict__ cellstart, const unsigned* __restrict__ pairs,
    int* __restrict__ srcs, int* __restrict__ rowstart, float* __restrict__ dinv, int n)
{
    __shared__ int hist[BKT_NODES];
    __shared__ int ofs[BKT_NODES];
    int b = blockIdx.x, tid = threadIdx.x;
    int beg = cellstart[b * NSLICE], end = cellstart[(b + 1) * NSLICE];
    hist[tid] = 0;
    __syncthreads();
    for (int e = beg + tid; e < end; e += 256)
        atomicAdd(&hist[pairs[e] & (BKT_NODES - 1)], 1);
    __syncthreads();
    int my = hist[tid];
    ofs[tid] = my;
    __syncthreads();
    for (int off = 1; off < 256; off <<= 1) {
        int t = (tid >= off) ? ofs[tid - off] : 0;
        __syncthreads();
        ofs[tid] += t;
        __syncthreads();
    }
    int excl = ofs[tid] - my;         // exclusive local offset
    int node = b * BKT_NODES + tid;
    if (node < n) {
        rowstart[node] = beg + excl;
        dinv[node] = rsqrtf((float)(my + 1));   // +1 self-loop
    }
    __syncthreads();
    ofs[tid] = excl;                  // reuse as LDS cursor
    __syncthreads();
    for (int e = beg + tid; e < end; e += 256) {
        unsigned p = pairs[e];
        int dl = p & (BKT_NODES - 1);
        int pos = beg + atomicAdd(&ofs[dl], 1);
        srcs[pos] = (int)(p >> BKT_SHIFT);
    }
}

// ================= xs[i][j] = dinv[i] * x[i][j]  (float4) =================
__global__ void xs_kernel(const float* __restrict__ x, const float* __restrict__ dinv,
                          float* __restrict__ xs, int n) {
    int t = blockIdx.x * blockDim.x + threadIdx.x;
    if (t < n * (IN_F / 4)) {
        float d = dinv[t >> 3];
        float4 v = ((const float4*)x)[t];
        v.x *= d; v.y *= d; v.z *= d; v.w *= d;
        ((float4*)xs)[t] = v;
    }
}

// ================= fused1: gather xs -> g -> W1+relu -> W2 -> hs2 =================
// 8 nodes/block, half-wave (32 lanes) per node, lane = feature j.
__global__ __launch_bounds__(256) void fused1_kernel(
    const int* __restrict__ rowstart, const int* __restrict__ srcs,
    const float* __restrict__ xs, const float* __restrict__ dinv,
    const float* __restrict__ b1, const float* __restrict__ W1,
    const float* __restrict__ W2, float* __restrict__ hs2, int n)
{
    __shared__ float W1s[IN_F * HID_F];    // 8 KB  [k*64+j]
    __shared__ float W2s[HID_F * OUT_F];   // 8 KB  [k*32+j]
    __shared__ float grow[8][IN_F];
    __shared__ float hrow[8][HID_F];
    int tid = threadIdx.x;
    for (int t = tid; t < IN_F * HID_F; t += 256) W1s[t] = W1[t];
    for (int t = tid; t < HID_F * OUT_F; t += 256) W2s[t] = W2[t];

    int sub = tid >> 5, j = tid & 31;
    int node = blockIdx.x * 8 + sub;
    bool active = node < n;
    int nodec = active ? node : 0;

    int beg = rowstart[nodec], end = active ? rowstart[nodec + 1] : beg;
    float a0 = active ? xs[(size_t)nodec * IN_F + j] : 0.f;   // self-loop
    float a1 = 0.f, a2 = 0.f, a3 = 0.f;
    int e = beg;
    for (; e + 4 <= end; e += 4) {
        int s0 = srcs[e], s1 = srcs[e + 1], s2 = srcs[e + 2], s3 = srcs[e + 3];
        a0 += xs[(size_t)s0 * IN_F + j];
        a1 += xs[(size_t)s1 * IN_F + j];
        a2 += xs[(size_t)s2 * IN_F + j];
        a3 += xs[(size_t)s3 * IN_F + j];
    }
    for (; e < end; ++e) a0 += xs[(size_t)srcs[e] * IN_F + j];
    float dv = dinv[nodec];
    grow[sub][j] = dv * ((a0 + a1) + (a2 + a3));
    __syncthreads();

    float h0 = b1[j], h1v = b1[j + 32];
    #pragma unroll
    for (int k = 0; k < IN_F; ++k) {
        float gk = grow[sub][k];
        h0  += gk * W1s[k * HID_F + j];
        h1v += gk * W1s[k * HID_F + j + 32];
    }
    hrow[sub][j]      = fmaxf(h0, 0.f);
    hrow[sub][j + 32] = fmaxf(h1v, 0.f);
    __syncthreads();

    float p = 0.f;
    #pragma unroll
    for (int k = 0; k < HID_F; ++k) p += hrow[sub][k] * W2s[k * OUT_F + j];
    if (active) hs2[(size_t)node * OUT_F + j] = dv * p;
}

// ================= agg2: gather hs2 + self, finalize =================
__global__ __launch_bounds__(256) void agg2_kernel(
    const int* __restrict__ rowstart, const int* __restrict__ srcs,
    const float* __restrict__ hs2, const float* __restrict__ dinv,
    const float* __restrict__ b2, float* __restrict__ out, int n)
{
    int t = blockIdx.x * blockDim.x + threadIdx.x;
    int node = t >> 5;
    if (node >= n) return;
    int j = t & 31;
    int beg = rowstart[node], end = rowstart[node + 1];
    float a0 = hs2[(size_t)node * OUT_F + j];   // self-loop
    float a1 = 0.f, a2 = 0.f, a3 = 0.f;
    int e = beg;
    for (; e + 4 <= end; e += 4) {
        int s0 = srcs[e], s1 = srcs[e + 1], s2 = srcs[e + 2], s3 = srcs[e + 3];
        a0 += hs2[(size_t)s0 * OUT_F + j];
        a1 += hs2[(size_t)s1 * OUT_F + j];
        a2 += hs2[(size_t)s2 * OUT_F + j];
        a3 += hs2[(size_t)s3 * OUT_F + j];
    }
    for (; e < end; ++e) a0 += hs2[(size_t)srcs[e] * OUT_F + j];
    out[(size_t)node * OUT_F + j] = dinv[node] * ((a0 + a1) + (a2 + a3)) + b2[j];
}

extern "C" void kernel_launch(void* const* d_in, const int* in_sizes, int n_in,
                              void* d_out, int out_size, void* d_ws, size_t ws_size,
                              hipStream_t stream) {
    const float* x  = (const float*)d_in[0];
    const int*   ei = (const int*)  d_in[1];
    const float* W1 = (const float*)d_in[2];
    const float* b1 = (const float*)d_in[3];
    const float* W2 = (const float*)d_in[4];
    const float* b2 = (const float*)d_in[5];
    float* out = (float*)d_out;

    const int n = in_sizes[0] / IN_F;     // 100000
    const int E = in_sizes[1] / 2;        // 1600000
    const int* src = ei;
    const int* dst = ei + E;

    const int nb = (n + BKT_NODES - 1) >> BKT_SHIFT;   // 391 buckets
    const int nc = nb * NSLICE;                        // 3128 cells

    // ---- workspace layout: ~39 MB ----
    int* ip = (int*)d_ws;
    int* cnt       = ip;                 ip += nc;         // zeroed
    int* cur       = ip;                 ip += nc;
    int* cellstart = ip;                 ip += nc + 1;
    int* rowstart  = ip;                 ip += n + 1;
    unsigned* pairs = (unsigned*)ip;     ip += E;          // 6.4 MB
    int* srcs_srt  = ip;                 ip += E;          // 6.4 MB
    float* fp = (float*)ip;
    float* dinv = fp;                    fp += n;
    float* xs   = fp;                    fp += (size_t)n * IN_F;    // 12.8 MB
    float* hs2  = fp;                    fp += (size_t)n * OUT_F;   // 12.8 MB

    hipMemsetAsync(cnt, 0, (size_t)nc * sizeof(int), stream);

    count_kernel    <<<GRID_PART, 256, 0, stream>>>(dst, cnt, E, nb);
    scancells_kernel<<<1, 1024, 0, stream>>>(cnt, cellstart, cur, nc, rowstart, n, E);
    append_kernel   <<<GRID_PART, 256, 0, stream>>>(src, dst, cur, pairs, E);
    place_kernel    <<<nb, 256, 0, stream>>>(cellstart, pairs, srcs_srt, rowstart, dinv, n);

    xs_kernel<<<((size_t)n * 8 + 255) / 256, 256, 0, stream>>>(x, dinv, xs, n);

    fused1_kernel<<<(n + 7) / 8, 256, 0, stream>>>(rowstart, srcs_srt, xs, dinv, b1, W1, W2, hs2, n);
    agg2_kernel<<<((size_t)n * 32 + 255) / 256, 256, 0, stream>>>(rowstart, srcs_srt, hs2, dinv, b2, out, n);
}

// Round 6
// 350.610 us; speedup vs baseline: 1.1479x; 1.1479x over previous
//
#include <hip/hip_runtime.h>

#define IN_F  32
#define HID_F 64
#define OUT_F 32

#define BKT_SHIFT 8            // 256 nodes per bucket
#define BKT_NODES 256
#define NBLK      128          // partition blocks — count/append edge->block map MUST match

// ================= phase 1: per-(bucket,block) exact counts =================
// cell = bucket*NBLK + block (bucket-major). Plain stores, no global atomics.
__global__ __launch_bounds__(256) void count_kernel(const int* __restrict__ dst,
                                                    int* __restrict__ cnt, int E, int nb)
{
    __shared__ int hist[1024];          // nb <= 1024 (n <= 262144)
    int tid = threadIdx.x;
    for (int i = tid; i < nb; i += 256) hist[i] = 0;
    __syncthreads();
    for (int e = blockIdx.x * 256 + tid; e < E; e += NBLK * 256)
        atomicAdd(&hist[dst[e] >> BKT_SHIFT], 1);
    __syncthreads();
    for (int i = tid; i < nb; i += 256) cnt[i * NBLK + blockIdx.x] = hist[i];
}

// ================= phase 2: one-block scan of nc = nb*NBLK cells =================
__global__ __launch_bounds__(1024) void scancells_kernel(
    const int* __restrict__ cnt, int* __restrict__ cellstart,
    int nc, int* __restrict__ rowstart, int n, int E)
{
    __shared__ int ts[1024];
    int tid = threadIdx.x;
    int chunk = (nc + 1023) >> 10;
    int lo = tid * chunk, hi = min(lo + chunk, nc);
    int sum = 0;
    for (int i = lo; i < hi; ++i) sum += cnt[i];
    ts[tid] = sum;
    __syncthreads();
    for (int off = 1; off < 1024; off <<= 1) {
        int t = (tid >= off) ? ts[tid - off] : 0;
        __syncthreads();
        ts[tid] += t;
        __syncthreads();
    }
    int run = ts[tid] - sum;            // exclusive prefix of this thread's chunk
    for (int i = lo; i < hi; ++i) { cellstart[i] = run; run += cnt[i]; }
    if (tid == 0) { cellstart[nc] = E; rowstart[n] = E; }
}

// ================= phase 3: append via block-private LDS cursors =================
// Each (bucket,block) range is written by exactly one block -> lines fill before
// eviction. pack = (src << 8) | (dst & 255), src < 2^24.
__global__ __launch_bounds__(256) void append_kernel(
    const int* __restrict__ src, const int* __restrict__ dst,
    const int* __restrict__ cellstart, unsigned* __restrict__ pairs, int E, int nb)
{
    __shared__ int cur[1024];
    int tid = threadIdx.x;
    for (int i = tid; i < nb; i += 256) cur[i] = cellstart[i * NBLK + blockIdx.x];
    __syncthreads();
    for (int e = blockIdx.x * 256 + tid; e < E; e += NBLK * 256) {
        int d = dst[e];
        int pos = atomicAdd(&cur[d >> BKT_SHIFT], 1);     // LDS atomic
        pairs[pos] = ((unsigned)src[e] << BKT_SHIFT) | (unsigned)(d & (BKT_NODES - 1));
    }
}

// ================= phase 4: per-bucket place + rowstart + dinv =================
// One block per bucket. Bucket b's pairs live at [cellstart[b*NBLK], cellstart[(b+1)*NBLK])
// (contiguous, bucket-major cells); its CSR window starts there too.
__global__ __launch_bounds__(256) void place_kernel(
    const int* __restrict__ cellstart, const unsigned* __restrict__ pairs,
    int* __restrict__ srcs, int* __restrict__ rowstart, float* __restrict__ dinv, int n)
{
    __shared__ int hist[BKT_NODES];
    __shared__ int ofs[BKT_NODES];
    int b = blockIdx.x, tid = threadIdx.x;
    int beg = cellstart[b * NBLK], end = cellstart[(b + 1) * NBLK];
    hist[tid] = 0;
    __syncthreads();
    for (int e = beg + tid; e < end; e += 256)
        atomicAdd(&hist[pairs[e] & (BKT_NODES - 1)], 1);
    __syncthreads();
    int my = hist[tid];
    ofs[tid] = my;
    __syncthreads();
    for (int off = 1; off < 256; off <<= 1) {
        int t = (tid >= off) ? ofs[tid - off] : 0;
        __syncthreads();
        ofs[tid] += t;
        __syncthreads();
    }
    int excl = ofs[tid] - my;           // exclusive local offset
    int node = b * BKT_NODES + tid;
    if (node < n) {
        rowstart[node] = beg + excl;
        dinv[node] = rsqrtf((float)(my + 1));   // +1 self-loop
    }
    __syncthreads();
    ofs[tid] = excl;                    // reuse as LDS cursor
    __syncthreads();
    for (int e = beg + tid; e < end; e += 256) {
        unsigned p = pairs[e];
        int dl = p & (BKT_NODES - 1);
        int pos = beg + atomicAdd(&ofs[dl], 1);
        srcs[pos] = (int)(p >> BKT_SHIFT);
    }
}

// ================= xs[i][j] = dinv[i] * x[i][j]  (float4) =================
__global__ void xs_kernel(const float* __restrict__ x, const float* __restrict__ dinv,
                          float* __restrict__ xs, int n) {
    int t = blockIdx.x * blockDim.x + threadIdx.x;
    if (t < n * (IN_F / 4)) {
        float d = dinv[t >> 3];
        float4 v = ((const float4*)x)[t];
        v.x *= d; v.y *= d; v.z *= d; v.w *= d;
        ((float4*)xs)[t] = v;
    }
}

// ================= fused1: gather xs -> g -> W1+relu -> W2 -> hs2 =================
// 8 nodes/block, half-wave (32 lanes) per node, lane = feature j.
__global__ __launch_bounds__(256) void fused1_kernel(
    const int* __restrict__ rowstart, const int* __restrict__ srcs,
    const float* __restrict__ xs, const float* __restrict__ dinv,
    const float* __restrict__ b1, const float* __restrict__ W1,
    const float* __restrict__ W2, float* __restrict__ hs2, int n)
{
    __shared__ float W1s[IN_F * HID_F];    // 8 KB  [k*64+j]
    __shared__ float W2s[HID_F * OUT_F];   // 8 KB  [k*32+j]
    __shared__ float grow[8][IN_F];
    __shared__ float hrow[8][HID_F];
    int tid = threadIdx.x;
    for (int t = tid; t < IN_F * HID_F; t += 256) W1s[t] = W1[t];
    for (int t = tid; t < HID_F * OUT_F; t += 256) W2s[t] = W2[t];

    int sub = tid >> 5, j = tid & 31;
    int node = blockIdx.x * 8 + sub;
    bool active = node < n;
    int nodec = active ? node : 0;

    int beg = rowstart[nodec], end = active ? rowstart[nodec + 1] : beg;
    float a0 = active ? xs[(size_t)nodec * IN_F + j] : 0.f;   // self-loop
    float a1 = 0.f, a2 = 0.f, a3 = 0.f;
    int e = beg;
    for (; e + 4 <= end; e += 4) {
        int s0 = srcs[e], s1 = srcs[e + 1], s2 = srcs[e + 2], s3 = srcs[e + 3];
        a0 += xs[(size_t)s0 * IN_F + j];
        a1 += xs[(size_t)s1 * IN_F + j];
        a2 += xs[(size_t)s2 * IN_F + j];
        a3 += xs[(size_t)s3 * IN_F + j];
    }
    for (; e < end; ++e) a0 += xs[(size_t)srcs[e] * IN_F + j];
    float dv = dinv[nodec];
    grow[sub][j] = dv * ((a0 + a1) + (a2 + a3));
    __syncthreads();

    float h0 = b1[j], h1v = b1[j + 32];
    #pragma unroll
    for (int k = 0; k < IN_F; ++k) {
        float gk = grow[sub][k];
        h0  += gk * W1s[k * HID_F + j];
        h1v += gk * W1s[k * HID_F + j + 32];
    }
    hrow[sub][j]      = fmaxf(h0, 0.f);
    hrow[sub][j + 32] = fmaxf(h1v, 0.f);
    __syncthreads();

    float p = 0.f;
    #pragma unroll
    for (int k = 0; k < HID_F; ++k) p += hrow[sub][k] * W2s[k * OUT_F + j];
    if (active) hs2[(size_t)node * OUT_F + j] = dv * p;
}

// ================= agg2: gather hs2 + self, finalize =================
__global__ __launch_bounds__(256) void agg2_kernel(
    const int* __restrict__ rowstart, const int* __restrict__ srcs,
    const float* __restrict__ hs2, const float* __restrict__ dinv,
    const float* __restrict__ b2, float* __restrict__ out, int n)
{
    int t = blockIdx.x * blockDim.x + threadIdx.x;
    int node = t >> 5;
    if (node >= n) return;
    int j = t & 31;
    int beg = rowstart[node], end = rowstart[node + 1];
    float a0 = hs2[(size_t)node * OUT_F + j];   // self-loop
    float a1 = 0.f, a2 = 0.f, a3 = 0.f;
    int e = beg;
    for (; e + 4 <= end; e += 4) {
        int s0 = srcs[e], s1 = srcs[e + 1], s2 = srcs[e + 2], s3 = srcs[e + 3];
        a0 += hs2[(size_t)s0 * OUT_F + j];
        a1 += hs2[(size_t)s1 * OUT_F + j];
        a2 += hs2[(size_t)s2 * OUT_F + j];
        a3 += hs2[(size_t)s3 * OUT_F + j];
    }
    for (; e < end; ++e) a0 += hs2[(size_t)srcs[e] * OUT_F + j];
    out[(size_t)node * OUT_F + j] = dinv[node] * ((a0 + a1) + (a2 + a3)) + b2[j];
}

extern "C" void kernel_launch(void* const* d_in, const int* in_sizes, int n_in,
                              void* d_out, int out_size, void* d_ws, size_t ws_size,
                              hipStream_t stream) {
    const float* x  = (const float*)d_in[0];
    const int*   ei = (const int*)  d_in[1];
    const float* W1 = (const float*)d_in[2];
    const float* b1 = (const float*)d_in[3];
    const float* W2 = (const float*)d_in[4];
    const float* b2 = (const float*)d_in[5];
    float* out = (float*)d_out;

    const int n = in_sizes[0] / IN_F;     // 100000
    const int E = in_sizes[1] / 2;        // 1600000
    const int* src = ei;
    const int* dst = ei + E;

    const int nb = (n + BKT_NODES - 1) >> BKT_SHIFT;   // 391 buckets
    const int nc = nb * NBLK;                          // 50048 cells

    // ---- workspace layout: ~40 MB ----
    int* ip = (int*)d_ws;
    int* cnt       = ip;                 ip += nc;
    int* cellstart = ip;                 ip += nc + 1;
    int* rowstart  = ip;                 ip += n + 1;
    unsigned* pairs = (unsigned*)ip;     ip += E;          // 6.4 MB
    int* srcs_srt  = ip;                 ip += E;          // 6.4 MB
    float* fp = (float*)ip;
    float* dinv = fp;                    fp += n;
    float* xs   = fp;                    fp += (size_t)n * IN_F;    // 12.8 MB
    float* hs2  = fp;                    fp += (size_t)n * OUT_F;   // 12.8 MB

    count_kernel    <<<NBLK, 256, 0, stream>>>(dst, cnt, E, nb);
    scancells_kernel<<<1, 1024, 0, stream>>>(cnt, cellstart, nc, rowstart, n, E);
    append_kernel   <<<NBLK, 256, 0, stream>>>(src, dst, cellstart, pairs, E, nb);
    place_kernel    <<<nb, 256, 0, stream>>>(cellstart, pairs, srcs_srt, rowstart, dinv, n);

    xs_kernel<<<((size_t)n * 8 + 255) / 256, 256, 0, stream>>>(x, dinv, xs, n);

    fused1_kernel<<<(n + 7) / 8, 256, 0, stream>>>(rowstart, srcs_srt, xs, dinv, b1, W1, W2, hs2, n);
    agg2_kernel<<<((size_t)n * 32 + 255) / 256, 256, 0, stream>>>(rowstart, srcs_srt, hs2, dinv, b2, out, n);
}

// Round 7
// 333.457 us; speedup vs baseline: 1.2070x; 1.0514x over previous
//
#include <hip/hip_runtime.h>

#define IN_F  32
#define HID_F 64
#define OUT_F 32

#define BKT_SHIFT 8            // 256 nodes per bucket
#define BKT_NODES 256
#define NBLK      128          // partition blocks — count/append edge->block map MUST match

// bf16 helpers (round-to-nearest-even; inputs are finite)
__device__ inline unsigned short f2bf(float f) {
    unsigned u = __float_as_uint(f);
    return (unsigned short)((u + 0x7FFF + ((u >> 16) & 1)) >> 16);
}
__device__ inline float bf2f(unsigned short h) {
    return __uint_as_float(((unsigned)h) << 16);
}

// ================= phase 1: per-(bucket,block) exact counts =================
__global__ __launch_bounds__(256) void count_kernel(const int* __restrict__ dst,
                                                    int* __restrict__ cnt, int E, int nb)
{
    __shared__ int hist[1024];          // nb <= 1024 (n <= 262144)
    int tid = threadIdx.x;
    for (int i = tid; i < nb; i += 256) hist[i] = 0;
    __syncthreads();
    for (int e = blockIdx.x * 256 + tid; e < E; e += NBLK * 256)
        atomicAdd(&hist[dst[e] >> BKT_SHIFT], 1);
    __syncthreads();
    for (int i = tid; i < nb; i += 256) cnt[i * NBLK + blockIdx.x] = hist[i];
}

// ================= phase 2: one-block scan of nc = nb*NBLK cells =================
__global__ __launch_bounds__(1024) void scancells_kernel(
    const int* __restrict__ cnt, int* __restrict__ cellstart,
    int nc, int* __restrict__ rowstart, int n, int E)
{
    __shared__ int ts[1024];
    int tid = threadIdx.x;
    int chunk = (nc + 1023) >> 10;
    int lo = tid * chunk, hi = min(lo + chunk, nc);
    int sum = 0;
    for (int i = lo; i < hi; ++i) sum += cnt[i];
    ts[tid] = sum;
    __syncthreads();
    for (int off = 1; off < 1024; off <<= 1) {
        int t = (tid >= off) ? ts[tid - off] : 0;
        __syncthreads();
        ts[tid] += t;
        __syncthreads();
    }
    int run = ts[tid] - sum;
    for (int i = lo; i < hi; ++i) { cellstart[i] = run; run += cnt[i]; }
    if (tid == 0) { cellstart[nc] = E; rowstart[n] = E; }
}

// ================= phase 3: append via block-private LDS cursors =================
__global__ __launch_bounds__(256) void append_kernel(
    const int* __restrict__ src, const int* __restrict__ dst,
    const int* __restrict__ cellstart, unsigned* __restrict__ pairs, int E, int nb)
{
    __shared__ int cur[1024];
    int tid = threadIdx.x;
    for (int i = tid; i < nb; i += 256) cur[i] = cellstart[i * NBLK + blockIdx.x];
    __syncthreads();
    for (int e = blockIdx.x * 256 + tid; e < E; e += NBLK * 256) {
        int d = dst[e];
        int pos = atomicAdd(&cur[d >> BKT_SHIFT], 1);     // LDS atomic
        pairs[pos] = ((unsigned)src[e] << BKT_SHIFT) | (unsigned)(d & (BKT_NODES - 1));
    }
}

// ================= phase 4: per-bucket place + rowstart + dinv =================
__global__ __launch_bounds__(256) void place_kernel(
    const int* __restrict__ cellstart, const unsigned* __restrict__ pairs,
    int* __restrict__ srcs, int* __restrict__ rowstart, float* __restrict__ dinv, int n)
{
    __shared__ int hist[BKT_NODES];
    __shared__ int ofs[BKT_NODES];
    int b = blockIdx.x, tid = threadIdx.x;
    int beg = cellstart[b * NBLK], end = cellstart[(b + 1) * NBLK];
    hist[tid] = 0;
    __syncthreads();
    for (int e = beg + tid; e < end; e += 256)
        atomicAdd(&hist[pairs[e] & (BKT_NODES - 1)], 1);
    __syncthreads();
    int my = hist[tid];
    ofs[tid] = my;
    __syncthreads();
    for (int off = 1; off < 256; off <<= 1) {
        int t = (tid >= off) ? ofs[tid - off] : 0;
        __syncthreads();
        ofs[tid] += t;
        __syncthreads();
    }
    int excl = ofs[tid] - my;
    int node = b * BKT_NODES + tid;
    if (node < n) {
        rowstart[node] = beg + excl;
        dinv[node] = rsqrtf((float)(my + 1));   // +1 self-loop
    }
    __syncthreads();
    ofs[tid] = excl;                    // reuse as LDS cursor
    __syncthreads();
    for (int e = beg + tid; e < end; e += 256) {
        unsigned p = pairs[e];
        int dl = p & (BKT_NODES - 1);
        int pos = beg + atomicAdd(&ofs[dl], 1);
        srcs[pos] = (int)(p >> BKT_SHIFT);
    }
}

// ================= xs[i][j] = bf16(dinv[i] * x[i][j]) =================
__global__ void xs_kernel(const float* __restrict__ x, const float* __restrict__ dinv,
                          unsigned short* __restrict__ xsb, int n) {
    int t = blockIdx.x * blockDim.x + threadIdx.x;
    if (t < n * (IN_F / 4)) {
        float d = dinv[t >> 3];
        float4 v = ((const float4*)x)[t];
        ushort4 o;
        o.x = f2bf(v.x * d); o.y = f2bf(v.y * d);
        o.z = f2bf(v.z * d); o.w = f2bf(v.w * d);
        ((ushort4*)xsb)[t] = o;
    }
}

// ================= fused1: gather bf16 xs -> g -> W1+relu -> W2 -> bf16 hs2 =================
// 8 nodes/block, half-wave (32 lanes) per node, lane = feature j. Gather row = 64 B = 1 line.
__global__ __launch_bounds__(256) void fused1_kernel(
    const int* __restrict__ rowstart, const int* __restrict__ srcs,
    const unsigned short* __restrict__ xsb, const float* __restrict__ dinv,
    const float* __restrict__ b1, const float* __restrict__ W1,
    const float* __restrict__ W2, unsigned short* __restrict__ hs2b, int n)
{
    __shared__ float W1s[IN_F * HID_F];    // 8 KB  [k*64+j]
    __shared__ float W2s[HID_F * OUT_F];   // 8 KB  [k*32+j]
    __shared__ float grow[8][IN_F];
    __shared__ float hrow[8][HID_F];
    int tid = threadIdx.x;
    for (int t = tid; t < IN_F * HID_F; t += 256) W1s[t] = W1[t];
    for (int t = tid; t < HID_F * OUT_F; t += 256) W2s[t] = W2[t];

    int sub = tid >> 5, j = tid & 31;
    int node = blockIdx.x * 8 + sub;
    bool active = node < n;
    int nodec = active ? node : 0;

    int beg = rowstart[nodec], end = active ? rowstart[nodec + 1] : beg;
    float a0 = active ? bf2f(xsb[(size_t)nodec * IN_F + j]) : 0.f;   // self-loop
    float a1 = 0.f, a2 = 0.f, a3 = 0.f;
    int e = beg;
    for (; e + 4 <= end; e += 4) {
        int s0 = srcs[e], s1 = srcs[e + 1], s2 = srcs[e + 2], s3 = srcs[e + 3];
        a0 += bf2f(xsb[(size_t)s0 * IN_F + j]);
        a1 += bf2f(xsb[(size_t)s1 * IN_F + j]);
        a2 += bf2f(xsb[(size_t)s2 * IN_F + j]);
        a3 += bf2f(xsb[(size_t)s3 * IN_F + j]);
    }
    for (; e < end; ++e) a0 += bf2f(xsb[(size_t)srcs[e] * IN_F + j]);
    float dv = dinv[nodec];
    grow[sub][j] = dv * ((a0 + a1) + (a2 + a3));
    __syncthreads();

    float h0 = b1[j], h1v = b1[j + 32];
    #pragma unroll
    for (int k = 0; k < IN_F; ++k) {
        float gk = grow[sub][k];
        h0  += gk * W1s[k * HID_F + j];
        h1v += gk * W1s[k * HID_F + j + 32];
    }
    hrow[sub][j]      = fmaxf(h0, 0.f);
    hrow[sub][j + 32] = fmaxf(h1v, 0.f);
    __syncthreads();

    float p = 0.f;
    #pragma unroll
    for (int k = 0; k < HID_F; ++k) p += hrow[sub][k] * W2s[k * OUT_F + j];
    if (active) hs2b[(size_t)node * OUT_F + j] = f2bf(dv * p);
}

// ================= agg2: gather bf16 hs2 + self, finalize (fp32 out) =================
__global__ __launch_bounds__(256) void agg2_kernel(
    const int* __restrict__ rowstart, const int* __restrict__ srcs,
    const unsigned short* __restrict__ hs2b, const float* __restrict__ dinv,
    const float* __restrict__ b2, float* __restrict__ out, int n)
{
    int t = blockIdx.x * blockDim.x + threadIdx.x;
    int node = t >> 5;
    if (node >= n) return;
    int j = t & 31;
    int beg = rowstart[node], end = rowstart[node + 1];
    float a0 = bf2f(hs2b[(size_t)node * OUT_F + j]);   // self-loop
    float a1 = 0.f, a2 = 0.f, a3 = 0.f;
    int e = beg;
    for (; e + 4 <= end; e += 4) {
        int s0 = srcs[e], s1 = srcs[e + 1], s2 = srcs[e + 2], s3 = srcs[e + 3];
        a0 += bf2f(hs2b[(size_t)s0 * OUT_F + j]);
        a1 += bf2f(hs2b[(size_t)s1 * OUT_F + j]);
        a2 += bf2f(hs2b[(size_t)s2 * OUT_F + j]);
        a3 += bf2f(hs2b[(size_t)s3 * OUT_F + j]);
    }
    for (; e < end; ++e) a0 += bf2f(hs2b[(size_t)srcs[e] * OUT_F + j]);
    out[(size_t)node * OUT_F + j] = dinv[node] * ((a0 + a1) + (a2 + a3)) + b2[j];
}

extern "C" void kernel_launch(void* const* d_in, const int* in_sizes, int n_in,
                              void* d_out, int out_size, void* d_ws, size_t ws_size,
                              hipStream_t stream) {
    const float* x  = (const float*)d_in[0];
    const int*   ei = (const int*)  d_in[1];
    const float* W1 = (const float*)d_in[2];
    const float* b1 = (const float*)d_in[3];
    const float* W2 = (const float*)d_in[4];
    const float* b2 = (const float*)d_in[5];
    float* out = (float*)d_out;

    const int n = in_sizes[0] / IN_F;     // 100000
    const int E = in_sizes[1] / 2;        // 1600000
    const int* src = ei;
    const int* dst = ei + E;

    const int nb = (n + BKT_NODES - 1) >> BKT_SHIFT;   // 391 buckets
    const int nc = nb * NBLK;                          // 50048 cells

    // ---- workspace layout: ~24 MB ----
    int* ip = (int*)d_ws;
    int* cnt       = ip;                 ip += nc;
    int* cellstart = ip;                 ip += nc + 1;
    int* rowstart  = ip;                 ip += n + 1;
    unsigned* pairs = (unsigned*)ip;     ip += E;          // 6.4 MB
    int* srcs_srt  = ip;                 ip += E;          // 6.4 MB
    float* dinv = (float*)ip;            ip += n;
    unsigned short* xsb  = (unsigned short*)ip;            // 6.4 MB
    ip += (size_t)n * IN_F / 2;
    unsigned short* hs2b = (unsigned short*)ip;            // 6.4 MB

    count_kernel    <<<NBLK, 256, 0, stream>>>(dst, cnt, E, nb);
    scancells_kernel<<<1, 1024, 0, stream>>>(cnt, cellstart, nc, rowstart, n, E);
    append_kernel   <<<NBLK, 256, 0, stream>>>(src, dst, cellstart, pairs, E, nb);
    place_kernel    <<<nb, 256, 0, stream>>>(cellstart, pairs, srcs_srt, rowstart, dinv, n);

    xs_kernel<<<((size_t)n * 8 + 255) / 256, 256, 0, stream>>>(x, dinv, xsb, n);

    fused1_kernel<<<(n + 7) / 8, 256, 0, stream>>>(rowstart, srcs_srt, xsb, dinv, b1, W1, W2, hs2b, n);
    agg2_kernel<<<((size_t)n * 32 + 255) / 256, 256, 0, stream>>>(rowstart, srcs_srt, hs2b, dinv, b2, out, n);
}

// Round 8
// 322.113 us; speedup vs baseline: 1.2495x; 1.0352x over previous
//
#include <hip/hip_runtime.h>

#define IN_F  32
#define HID_F 64
#define OUT_F 32

#define BKT_SHIFT 8            // 256 nodes per bucket
#define BKT_NODES 256
#define NBLK      128          // partition blocks — count/append edge->block map MUST match

// bf16 helpers (round-to-nearest-even; inputs are finite)
__device__ inline unsigned short f2bf(float f) {
    unsigned u = __float_as_uint(f);
    return (unsigned short)((u + 0x7FFF + ((u >> 16) & 1)) >> 16);
}
__device__ inline float bf2f(unsigned short h) {
    return __uint_as_float(((unsigned)h) << 16);
}

// ================= phase 1: per-(bucket,block) exact counts =================
__global__ __launch_bounds__(256) void count_kernel(const int* __restrict__ dst,
                                                    int* __restrict__ cnt, int E, int nb)
{
    __shared__ int hist[1024];          // nb <= 1024 (n <= 262144)
    int tid = threadIdx.x;
    for (int i = tid; i < nb; i += 256) hist[i] = 0;
    __syncthreads();
    for (int e = blockIdx.x * 256 + tid; e < E; e += NBLK * 256)
        atomicAdd(&hist[dst[e] >> BKT_SHIFT], 1);
    __syncthreads();
    for (int i = tid; i < nb; i += 256) cnt[i * NBLK + blockIdx.x] = hist[i];
}

// ================= phase 2: one-block scan of nc = nb*NBLK cells =================
__global__ __launch_bounds__(1024) void scancells_kernel(
    const int* __restrict__ cnt, int* __restrict__ cellstart,
    int nc, int* __restrict__ rowstart, int n, int E)
{
    __shared__ int ts[1024];
    int tid = threadIdx.x;
    int chunk = (nc + 1023) >> 10;
    int lo = tid * chunk, hi = min(lo + chunk, nc);
    int sum = 0;
    for (int i = lo; i < hi; ++i) sum += cnt[i];
    ts[tid] = sum;
    __syncthreads();
    for (int off = 1; off < 1024; off <<= 1) {
        int t = (tid >= off) ? ts[tid - off] : 0;
        __syncthreads();
        ts[tid] += t;
        __syncthreads();
    }
    int run = ts[tid] - sum;
    for (int i = lo; i < hi; ++i) { cellstart[i] = run; run += cnt[i]; }
    if (tid == 0) { cellstart[nc] = E; rowstart[n] = E; }
}

// ================= phase 3: append via block-private LDS cursors =================
__global__ __launch_bounds__(256) void append_kernel(
    const int* __restrict__ src, const int* __restrict__ dst,
    const int* __restrict__ cellstart, unsigned* __restrict__ pairs, int E, int nb)
{
    __shared__ int cur[1024];
    int tid = threadIdx.x;
    for (int i = tid; i < nb; i += 256) cur[i] = cellstart[i * NBLK + blockIdx.x];
    __syncthreads();
    for (int e = blockIdx.x * 256 + tid; e < E; e += NBLK * 256) {
        int d = dst[e];
        int pos = atomicAdd(&cur[d >> BKT_SHIFT], 1);     // LDS atomic
        pairs[pos] = ((unsigned)src[e] << BKT_SHIFT) | (unsigned)(d & (BKT_NODES - 1));
    }
}

// ================= phase 4: per-bucket place + rowstart + dinv =================
__global__ __launch_bounds__(256) void place_kernel(
    const int* __restrict__ cellstart, const unsigned* __restrict__ pairs,
    int* __restrict__ srcs, int* __restrict__ rowstart, float* __restrict__ dinv, int n)
{
    __shared__ int hist[BKT_NODES];
    __shared__ int ofs[BKT_NODES];
    int b = blockIdx.x, tid = threadIdx.x;
    int beg = cellstart[b * NBLK], end = cellstart[(b + 1) * NBLK];
    hist[tid] = 0;
    __syncthreads();
    for (int e = beg + tid; e < end; e += 256)
        atomicAdd(&hist[pairs[e] & (BKT_NODES - 1)], 1);
    __syncthreads();
    int my = hist[tid];
    ofs[tid] = my;
    __syncthreads();
    for (int off = 1; off < 256; off <<= 1) {
        int t = (tid >= off) ? ofs[tid - off] : 0;
        __syncthreads();
        ofs[tid] += t;
        __syncthreads();
    }
    int excl = ofs[tid] - my;
    int node = b * BKT_NODES + tid;
    if (node < n) {
        rowstart[node] = beg + excl;
        dinv[node] = rsqrtf((float)(my + 1));   // +1 self-loop
    }
    __syncthreads();
    ofs[tid] = excl;                    // reuse as LDS cursor
    __syncthreads();
    for (int e = beg + tid; e < end; e += 256) {
        unsigned p = pairs[e];
        int dl = p & (BKT_NODES - 1);
        int pos = beg + atomicAdd(&ofs[dl], 1);
        srcs[pos] = (int)(p >> BKT_SHIFT);
    }
}

// ================= xs[i][j] = bf16(dinv[i] * x[i][j]) =================
__global__ void xs_kernel(const float* __restrict__ x, const float* __restrict__ dinv,
                          unsigned short* __restrict__ xsb, int n) {
    int t = blockIdx.x * blockDim.x + threadIdx.x;
    if (t < n * (IN_F / 4)) {
        float d = dinv[t >> 3];
        float4 v = ((const float4*)x)[t];
        ushort4 o;
        o.x = f2bf(v.x * d); o.y = f2bf(v.y * d);
        o.z = f2bf(v.z * d); o.w = f2bf(v.w * d);
        ((ushort4*)xsb)[t] = o;
    }
}

// ================= fused1: gather bf16 xs -> g -> W1+relu -> W2 -> bf16 hs2 =================
// 8 nodes/block, half-wave (32 lanes) per node, lane = feature j.
// unroll-8 gather: 8 independent 64B-line fetches in flight per chain.
__global__ __launch_bounds__(256) void fused1_kernel(
    const int* __restrict__ rowstart, const int* __restrict__ srcs,
    const unsigned short* __restrict__ xsb, const float* __restrict__ dinv,
    const float* __restrict__ b1, const float* __restrict__ W1,
    const float* __restrict__ W2, unsigned short* __restrict__ hs2b, int n)
{
    __shared__ float W1s[IN_F * HID_F];    // 8 KB  [k*64+j]
    __shared__ float W2s[HID_F * OUT_F];   // 8 KB  [k*32+j]
    __shared__ float grow[8][IN_F];
    __shared__ float hrow[8][HID_F];
    int tid = threadIdx.x;
    for (int t = tid; t < IN_F * HID_F; t += 256) W1s[t] = W1[t];
    for (int t = tid; t < HID_F * OUT_F; t += 256) W2s[t] = W2[t];

    int sub = tid >> 5, j = tid & 31;
    int node = blockIdx.x * 8 + sub;
    bool active = node < n;
    int nodec = active ? node : 0;

    int beg = rowstart[nodec], end = active ? rowstart[nodec + 1] : beg;
    float a0 = active ? bf2f(xsb[(size_t)nodec * IN_F + j]) : 0.f;   // self-loop
    float a1 = 0.f, a2 = 0.f, a3 = 0.f, a4 = 0.f, a5 = 0.f, a6 = 0.f, a7 = 0.f;
    int e = beg;
    for (; e + 8 <= end; e += 8) {
        int s0 = srcs[e],     s1 = srcs[e + 1], s2 = srcs[e + 2], s3 = srcs[e + 3];
        int s4 = srcs[e + 4], s5 = srcs[e + 5], s6 = srcs[e + 6], s7 = srcs[e + 7];
        a0 += bf2f(xsb[(size_t)s0 * IN_F + j]);
        a1 += bf2f(xsb[(size_t)s1 * IN_F + j]);
        a2 += bf2f(xsb[(size_t)s2 * IN_F + j]);
        a3 += bf2f(xsb[(size_t)s3 * IN_F + j]);
        a4 += bf2f(xsb[(size_t)s4 * IN_F + j]);
        a5 += bf2f(xsb[(size_t)s5 * IN_F + j]);
        a6 += bf2f(xsb[(size_t)s6 * IN_F + j]);
        a7 += bf2f(xsb[(size_t)s7 * IN_F + j]);
    }
    for (; e + 4 <= end; e += 4) {
        int s0 = srcs[e], s1 = srcs[e + 1], s2 = srcs[e + 2], s3 = srcs[e + 3];
        a0 += bf2f(xsb[(size_t)s0 * IN_F + j]);
        a1 += bf2f(xsb[(size_t)s1 * IN_F + j]);
        a2 += bf2f(xsb[(size_t)s2 * IN_F + j]);
        a3 += bf2f(xsb[(size_t)s3 * IN_F + j]);
    }
    for (; e < end; ++e) a0 += bf2f(xsb[(size_t)srcs[e] * IN_F + j]);
    float dv = dinv[nodec];
    grow[sub][j] = dv * (((a0 + a1) + (a2 + a3)) + ((a4 + a5) + (a6 + a7)));
    __syncthreads();

    float h0 = b1[j], h1v = b1[j + 32];
    #pragma unroll
    for (int k = 0; k < IN_F; ++k) {
        float gk = grow[sub][k];
        h0  += gk * W1s[k * HID_F + j];
        h1v += gk * W1s[k * HID_F + j + 32];
    }
    hrow[sub][j]      = fmaxf(h0, 0.f);
    hrow[sub][j + 32] = fmaxf(h1v, 0.f);
    __syncthreads();

    float p = 0.f;
    #pragma unroll
    for (int k = 0; k < HID_F; ++k) p += hrow[sub][k] * W2s[k * OUT_F + j];
    if (active) hs2b[(size_t)node * OUT_F + j] = f2bf(dv * p);
}

// ================= agg2: gather bf16 hs2 + self, finalize (fp32 out) =================
// unroll-8 gather, same rationale as fused1
__global__ __launch_bounds__(256) void agg2_kernel(
    const int* __restrict__ rowstart, const int* __restrict__ srcs,
    const unsigned short* __restrict__ hs2b, const float* __restrict__ dinv,
    const float* __restrict__ b2, float* __restrict__ out, int n)
{
    int t = blockIdx.x * blockDim.x + threadIdx.x;
    int node = t >> 5;
    if (node >= n) return;
    int j = t & 31;
    int beg = rowstart[node], end = rowstart[node + 1];
    float a0 = bf2f(hs2b[(size_t)node * OUT_F + j]);   // self-loop
    float a1 = 0.f, a2 = 0.f, a3 = 0.f, a4 = 0.f, a5 = 0.f, a6 = 0.f, a7 = 0.f;
    int e = beg;
    for (; e + 8 <= end; e += 8) {
        int s0 = srcs[e],     s1 = srcs[e + 1], s2 = srcs[e + 2], s3 = srcs[e + 3];
        int s4 = srcs[e + 4], s5 = srcs[e + 5], s6 = srcs[e + 6], s7 = srcs[e + 7];
        a0 += bf2f(hs2b[(size_t)s0 * OUT_F + j]);
        a1 += bf2f(hs2b[(size_t)s1 * OUT_F + j]);
        a2 += bf2f(hs2b[(size_t)s2 * OUT_F + j]);
        a3 += bf2f(hs2b[(size_t)s3 * OUT_F + j]);
        a4 += bf2f(hs2b[(size_t)s4 * OUT_F + j]);
        a5 += bf2f(hs2b[(size_t)s5 * OUT_F + j]);
        a6 += bf2f(hs2b[(size_t)s6 * OUT_F + j]);
        a7 += bf2f(hs2b[(size_t)s7 * OUT_F + j]);
    }
    for (; e + 4 <= end; e += 4) {
        int s0 = srcs[e], s1 = srcs[e + 1], s2 = srcs[e + 2], s3 = srcs[e + 3];
        a0 += bf2f(hs2b[(size_t)s0 * OUT_F + j]);
        a1 += bf2f(hs2b[(size_t)s1 * OUT_F + j]);
        a2 += bf2f(hs2b[(size_t)s2 * OUT_F + j]);
        a3 += bf2f(hs2b[(size_t)s3 * OUT_F + j]);
    }
    for (; e < end; ++e) a0 += bf2f(hs2b[(size_t)srcs[e] * OUT_F + j]);
    out[(size_t)node * OUT_F + j] =
        dinv[node] * (((a0 + a1) + (a2 + a3)) + ((a4 + a5) + (a6 + a7))) + b2[j];
}

extern "C" void kernel_launch(void* const* d_in, const int* in_sizes, int n_in,
                              void* d_out, int out_size, void* d_ws, size_t ws_size,
                              hipStream_t stream) {
    const float* x  = (const float*)d_in[0];
    const int*   ei = (const int*)  d_in[1];
    const float* W1 = (const float*)d_in[2];
    const float* b1 = (const float*)d_in[3];
    const float* W2 = (const float*)d_in[4];
    const float* b2 = (const float*)d_in[5];
    float* out = (float*)d_out;

    const int n = in_sizes[0] / IN_F;     // 100000
    const int E = in_sizes[1] / 2;        // 1600000
    const int* src = ei;
    const int* dst = ei + E;

    const int nb = (n + BKT_NODES - 1) >> BKT_SHIFT;   // 391 buckets
    const int nc = nb * NBLK;                          // 50048 cells

    // ---- workspace layout: ~24 MB ----
    int* ip = (int*)d_ws;
    int* cnt       = ip;                 ip += nc;
    int* cellstart = ip;                 ip += nc + 1;
    int* rowstart  = ip;                 ip += n + 1;
    unsigned* pairs = (unsigned*)ip;     ip += E;          // 6.4 MB
    int* srcs_srt  = ip;                 ip += E;          // 6.4 MB
    float* dinv = (float*)ip;            ip += n;
    unsigned short* xsb  = (unsigned short*)ip;            // 6.4 MB
    ip += (size_t)n * IN_F / 2;
    unsigned short* hs2b = (unsigned short*)ip;            // 6.4 MB

    count_kernel    <<<NBLK, 256, 0, stream>>>(dst, cnt, E, nb);
    scancells_kernel<<<1, 1024, 0, stream>>>(cnt, cellstart, nc, rowstart, n, E);
    append_kernel   <<<NBLK, 256, 0, stream>>>(src, dst, cellstart, pairs, E, nb);
    place_kernel    <<<nb, 256, 0, stream>>>(cellstart, pairs, srcs_srt, rowstart, dinv, n);

    xs_kernel<<<((size_t)n * 8 + 255) / 256, 256, 0, stream>>>(x, dinv, xsb, n);

    fused1_kernel<<<(n + 7) / 8, 256, 0, stream>>>(rowstart, srcs_srt, xsb, dinv, b1, W1, W2, hs2b, n);
    agg2_kernel<<<((size_t)n * 32 + 255) / 256, 256, 0, stream>>>(rowstart, srcs_srt, hs2b, dinv, b2, out, n);
}

// Round 9
// 256.354 us; speedup vs baseline: 1.5700x; 1.2565x over previous
//
#include <hip/hip_runtime.h>

#define IN_F  32
#define HID_F 64
#define OUT_F 32

#define BKT_SHIFT 8            // 256 nodes per bucket
#define BKT_NODES 256
#define NBLK      128          // partition blocks — count/append edge->block map MUST match

// bf16 helpers (round-to-nearest-even; inputs are finite)
__device__ inline unsigned short f2bf(float f) {
    unsigned u = __float_as_uint(f);
    return (unsigned short)((u + 0x7FFF + ((u >> 16) & 1)) >> 16);
}
__device__ inline float bf2f(unsigned short h) {
    return __uint_as_float(((unsigned)h) << 16);
}

// ================= phase 1: per-(bucket,block) exact counts =================
__global__ __launch_bounds__(256) void count_kernel(const int* __restrict__ dst,
                                                    int* __restrict__ cnt, int E, int nb)
{
    __shared__ int hist[1024];          // nb <= 1024
    int tid = threadIdx.x;
    for (int i = tid; i < nb; i += 256) hist[i] = 0;
    __syncthreads();
    for (int e = blockIdx.x * 256 + tid; e < E; e += NBLK * 256)
        atomicAdd(&hist[dst[e] >> BKT_SHIFT], 1);
    __syncthreads();
    for (int i = tid; i < nb; i += 256) cnt[i * NBLK + blockIdx.x] = hist[i];
}

// ================= phase 2a: per-bucket totals (one block per bucket) =================
__global__ __launch_bounds__(NBLK) void bsum_kernel(const int* __restrict__ cnt,
                                                    int* __restrict__ bsum)
{
    __shared__ int s[NBLK];
    int tid = threadIdx.x, b = blockIdx.x;
    s[tid] = cnt[b * NBLK + tid];
    __syncthreads();
    for (int off = NBLK / 2; off > 0; off >>= 1) {
        if (tid < off) s[tid] += s[tid + off];
        __syncthreads();
    }
    if (tid == 0) bsum[b] = s[0];
}

// ================= phase 2b: one-block exclusive scan of nb bucket totals =================
// nb <= 512 (n <= 131072). Also writes the sentinels.
__global__ __launch_bounds__(512) void bscan_kernel(int* __restrict__ bsum, int nb,
                                                    int* __restrict__ cellstart, int nc,
                                                    int* __restrict__ rowstart, int n, int E)
{
    __shared__ int s[512];
    int tid = threadIdx.x;
    int my = (tid < nb) ? bsum[tid] : 0;
    s[tid] = my;
    __syncthreads();
    for (int off = 1; off < 512; off <<= 1) {
        int t = (tid >= off) ? s[tid - off] : 0;
        __syncthreads();
        s[tid] += t;
        __syncthreads();
    }
    if (tid < nb) bsum[tid] = s[tid] - my;      // exclusive bucket start
    if (tid == 0) { cellstart[nc] = E; rowstart[n] = E; }
}

// ================= phase 2c: per-bucket scan of its 128 cells =================
__global__ __launch_bounds__(NBLK) void cscan_kernel(const int* __restrict__ cnt,
                                                     const int* __restrict__ bsum,
                                                     int* __restrict__ cellstart)
{
    __shared__ int s[NBLK];
    int tid = threadIdx.x, b = blockIdx.x;
    int my = cnt[b * NBLK + tid];
    s[tid] = my;
    __syncthreads();
    for (int off = 1; off < NBLK; off <<= 1) {
        int t = (tid >= off) ? s[tid - off] : 0;
        __syncthreads();
        s[tid] += t;
        __syncthreads();
    }
    cellstart[b * NBLK + tid] = bsum[b] + s[tid] - my;   // exclusive
}

// ================= phase 3: append via block-private LDS cursors =================
__global__ __launch_bounds__(256) void append_kernel(
    const int* __restrict__ src, const int* __restrict__ dst,
    const int* __restrict__ cellstart, unsigned* __restrict__ pairs, int E, int nb)
{
    __shared__ int cur[1024];
    int tid = threadIdx.x;
    for (int i = tid; i < nb; i += 256) cur[i] = cellstart[i * NBLK + blockIdx.x];
    __syncthreads();
    for (int e = blockIdx.x * 256 + tid; e < E; e += NBLK * 256) {
        int d = dst[e];
        int pos = atomicAdd(&cur[d >> BKT_SHIFT], 1);     // LDS atomic
        pairs[pos] = ((unsigned)src[e] << BKT_SHIFT) | (unsigned)(d & (BKT_NODES - 1));
    }
}

// ================= phase 4: per-bucket place + rowstart + dinv =================
__global__ __launch_bounds__(256) void place_kernel(
    const int* __restrict__ cellstart, const unsigned* __restrict__ pairs,
    int* __restrict__ srcs, int* __restrict__ rowstart, float* __restrict__ dinv, int n)
{
    __shared__ int hist[BKT_NODES];
    __shared__ int ofs[BKT_NODES];
    int b = blockIdx.x, tid = threadIdx.x;
    int beg = cellstart[b * NBLK], end = cellstart[(b + 1) * NBLK];
    hist[tid] = 0;
    __syncthreads();
    for (int e = beg + tid; e < end; e += 256)
        atomicAdd(&hist[pairs[e] & (BKT_NODES - 1)], 1);
    __syncthreads();
    int my = hist[tid];
    ofs[tid] = my;
    __syncthreads();
    for (int off = 1; off < 256; off <<= 1) {
        int t = (tid >= off) ? ofs[tid - off] : 0;
        __syncthreads();
        ofs[tid] += t;
        __syncthreads();
    }
    int excl = ofs[tid] - my;
    int node = b * BKT_NODES + tid;
    if (node < n) {
        rowstart[node] = beg + excl;
        dinv[node] = rsqrtf((float)(my + 1));   // +1 self-loop
    }
    __syncthreads();
    ofs[tid] = excl;                    // reuse as LDS cursor
    __syncthreads();
    for (int e = beg + tid; e < end; e += 256) {
        unsigned p = pairs[e];
        int dl = p & (BKT_NODES - 1);
        int pos = beg + atomicAdd(&ofs[dl], 1);
        srcs[pos] = (int)(p >> BKT_SHIFT);
    }
}

// ================= xs[i][j] = bf16(dinv[i] * x[i][j]) =================
__global__ void xs_kernel(const float* __restrict__ x, const float* __restrict__ dinv,
                          unsigned short* __restrict__ xsb, int n) {
    int t = blockIdx.x * blockDim.x + threadIdx.x;
    if (t < n * (IN_F / 4)) {
        float d = dinv[t >> 3];
        float4 v = ((const float4*)x)[t];
        ushort4 o;
        o.x = f2bf(v.x * d); o.y = f2bf(v.y * d);
        o.z = f2bf(v.z * d); o.w = f2bf(v.w * d);
        ((ushort4*)xsb)[t] = o;
    }
}

// ================= fused1: gather bf16 xs -> g -> W1+relu -> W2 -> bf16 hs2 =================
// 8 nodes/block, half-wave per node, lane = feature j. 32-bit gather offsets.
__global__ __launch_bounds__(256) void fused1_kernel(
    const int* __restrict__ rowstart, const int* __restrict__ srcs,
    const unsigned short* __restrict__ xsb, const float* __restrict__ dinv,
    const float* __restrict__ b1, const float* __restrict__ W1,
    const float* __restrict__ W2, unsigned short* __restrict__ hs2b, int n)
{
    __shared__ float W1s[IN_F * HID_F];    // 8 KB  [k*64+j]
    __shared__ float W2s[HID_F * OUT_F];   // 8 KB  [k*32+j]
    __shared__ float grow[8][IN_F];
    __shared__ float hrow[8][HID_F];
    int tid = threadIdx.x;
    for (int t = tid; t < IN_F * HID_F; t += 256) W1s[t] = W1[t];
    for (int t = tid; t < HID_F * OUT_F; t += 256) W2s[t] = W2[t];

    int sub = tid >> 5;
    unsigned j = tid & 31;
    int node = blockIdx.x * 8 + sub;
    bool active = node < n;
    int nodec = active ? node : 0;

    int beg = rowstart[nodec], end = active ? rowstart[nodec + 1] : beg;
    float a0 = active ? bf2f(xsb[((unsigned)nodec << 5) + j]) : 0.f;   // self-loop
    float a1 = 0.f, a2 = 0.f, a3 = 0.f, a4 = 0.f, a5 = 0.f, a6 = 0.f, a7 = 0.f;
    int e = beg;
    for (; e + 8 <= end; e += 8) {
        unsigned o0 = ((unsigned)srcs[e]     << 5) + j, o1 = ((unsigned)srcs[e + 1] << 5) + j;
        unsigned o2 = ((unsigned)srcs[e + 2] << 5) + j, o3 = ((unsigned)srcs[e + 3] << 5) + j;
        unsigned o4 = ((unsigned)srcs[e + 4] << 5) + j, o5 = ((unsigned)srcs[e + 5] << 5) + j;
        unsigned o6 = ((unsigned)srcs[e + 6] << 5) + j, o7 = ((unsigned)srcs[e + 7] << 5) + j;
        a0 += bf2f(xsb[o0]); a1 += bf2f(xsb[o1]);
        a2 += bf2f(xsb[o2]); a3 += bf2f(xsb[o3]);
        a4 += bf2f(xsb[o4]); a5 += bf2f(xsb[o5]);
        a6 += bf2f(xsb[o6]); a7 += bf2f(xsb[o7]);
    }
    for (; e + 4 <= end; e += 4) {
        unsigned o0 = ((unsigned)srcs[e]     << 5) + j, o1 = ((unsigned)srcs[e + 1] << 5) + j;
        unsigned o2 = ((unsigned)srcs[e + 2] << 5) + j, o3 = ((unsigned)srcs[e + 3] << 5) + j;
        a0 += bf2f(xsb[o0]); a1 += bf2f(xsb[o1]);
        a2 += bf2f(xsb[o2]); a3 += bf2f(xsb[o3]);
    }
    for (; e < end; ++e) a0 += bf2f(xsb[((unsigned)srcs[e] << 5) + j]);
    float dv = dinv[nodec];
    grow[sub][j] = dv * (((a0 + a1) + (a2 + a3)) + ((a4 + a5) + (a6 + a7)));
    __syncthreads();

    float h0 = b1[j], h1v = b1[j + 32];
    #pragma unroll
    for (int k = 0; k < IN_F; ++k) {
        float gk = grow[sub][k];
        h0  += gk * W1s[k * HID_F + j];
        h1v += gk * W1s[k * HID_F + j + 32];
    }
    hrow[sub][j]      = fmaxf(h0, 0.f);
    hrow[sub][j + 32] = fmaxf(h1v, 0.f);
    __syncthreads();

    float p = 0.f;
    #pragma unroll
    for (int k = 0; k < HID_F; ++k) p += hrow[sub][k] * W2s[k * OUT_F + j];
    if (active) hs2b[((unsigned)node << 5) + j] = f2bf(dv * p);
}

// ================= agg2: gather bf16 hs2 + self, finalize (fp32 out) =================
__global__ __launch_bounds__(256) void agg2_kernel(
    const int* __restrict__ rowstart, const int* __restrict__ srcs,
    const unsigned short* __restrict__ hs2b, const float* __restrict__ dinv,
    const float* __restrict__ b2, float* __restrict__ out, int n)
{
    int t = blockIdx.x * blockDim.x + threadIdx.x;
    int node = t >> 5;
    if (node >= n) return;
    unsigned j = t & 31;
    int beg = rowstart[node], end = rowstart[node + 1];
    float a0 = bf2f(hs2b[((unsigned)node << 5) + j]);   // self-loop
    float a1 = 0.f, a2 = 0.f, a3 = 0.f, a4 = 0.f, a5 = 0.f, a6 = 0.f, a7 = 0.f;
    int e = beg;
    for (; e + 8 <= end; e += 8) {
        unsigned o0 = ((unsigned)srcs[e]     << 5) + j, o1 = ((unsigned)srcs[e + 1] << 5) + j;
        unsigned o2 = ((unsigned)srcs[e + 2] << 5) + j, o3 = ((unsigned)srcs[e + 3] << 5) + j;
        unsigned o4 = ((unsigned)srcs[e + 4] << 5) + j, o5 = ((unsigned)srcs[e + 5] << 5) + j;
        unsigned o6 = ((unsigned)srcs[e + 6] << 5) + j, o7 = ((unsigned)srcs[e + 7] << 5) + j;
        a0 += bf2f(hs2b[o0]); a1 += bf2f(hs2b[o1]);
        a2 += bf2f(hs2b[o2]); a3 += bf2f(hs2b[o3]);
        a4 += bf2f(hs2b[o4]); a5 += bf2f(hs2b[o5]);
        a6 += bf2f(hs2b[o6]); a7 += bf2f(hs2b[o7]);
    }
    for (; e + 4 <= end; e += 4) {
        unsigned o0 = ((unsigned)srcs[e]     << 5) + j, o1 = ((unsigned)srcs[e + 1] << 5) + j;
        unsigned o2 = ((unsigned)srcs[e + 2] << 5) + j, o3 = ((unsigned)srcs[e + 3] << 5) + j;
        a0 += bf2f(hs2b[o0]); a1 += bf2f(hs2b[o1]);
        a2 += bf2f(hs2b[o2]); a3 += bf2f(hs2b[o3]);
    }
    for (; e < end; ++e) a0 += bf2f(hs2b[((unsigned)srcs[e] << 5) + j]);
    out[(size_t)node * OUT_F + j] =
        dinv[node] * (((a0 + a1) + (a2 + a3)) + ((a4 + a5) + (a6 + a7))) + b2[j];
}

extern "C" void kernel_launch(void* const* d_in, const int* in_sizes, int n_in,
                              void* d_out, int out_size, void* d_ws, size_t ws_size,
                              hipStream_t stream) {
    const float* x  = (const float*)d_in[0];
    const int*   ei = (const int*)  d_in[1];
    const float* W1 = (const float*)d_in[2];
    const float* b1 = (const float*)d_in[3];
    const float* W2 = (const float*)d_in[4];
    const float* b2 = (const float*)d_in[5];
    float* out = (float*)d_out;

    const int n = in_sizes[0] / IN_F;     // 100000
    const int E = in_sizes[1] / 2;        // 1600000
    const int* src = ei;
    const int* dst = ei + E;

    const int nb = (n + BKT_NODES - 1) >> BKT_SHIFT;   // 391 buckets (<=512)
    const int nc = nb * NBLK;                          // 50048 cells

    // ---- workspace layout: ~24 MB ----
    int* ip = (int*)d_ws;
    int* cnt       = ip;                 ip += nc;
    int* cellstart = ip;                 ip += nc + 1;
    int* bsum      = ip;                 ip += nb + 1;
    int* rowstart  = ip;                 ip += n + 1;
    unsigned* pairs = (unsigned*)ip;     ip += E;          // 6.4 MB
    int* srcs_srt  = ip;                 ip += E;          // 6.4 MB
    float* dinv = (float*)ip;            ip += n;
    unsigned short* xsb  = (unsigned short*)ip;            // 6.4 MB
    ip += (size_t)n * IN_F / 2;
    unsigned short* hs2b = (unsigned short*)ip;            // 6.4 MB

    count_kernel<<<NBLK, 256, 0, stream>>>(dst, cnt, E, nb);
    bsum_kernel <<<nb, NBLK, 0, stream>>>(cnt, bsum);
    bscan_kernel<<<1, 512, 0, stream>>>(bsum, nb, cellstart, nc, rowstart, n, E);
    cscan_kernel<<<nb, NBLK, 0, stream>>>(cnt, bsum, cellstart);
    append_kernel<<<NBLK, 256, 0, stream>>>(src, dst, cellstart, pairs, E, nb);
    place_kernel<<<nb, 256, 0, stream>>>(cellstart, pairs, srcs_srt, rowstart, dinv, n);

    xs_kernel<<<((size_t)n * 8 + 255) / 256, 256, 0, stream>>>(x, dinv, xsb, n);

    fused1_kernel<<<(n + 7) / 8, 256, 0, stream>>>(rowstart, srcs_srt, xsb, dinv, b1, W1, W2, hs2b, n);
    agg2_kernel<<<((size_t)n * 32 + 255) / 256, 256, 0, stream>>>(rowstart, srcs_srt, hs2b, dinv, b2, out, n);
}

// Round 10
// 235.201 us; speedup vs baseline: 1.7112x; 1.0899x over previous
//
#include <hip/hip_runtime.h>

#define IN_F  32
#define HID_F 64
#define OUT_F 32

#define BKT_SHIFT 8            // 256 nodes per bucket
#define BKT_NODES 256
#define NBLK      128          // partition blocks — count/append edge->block map MUST match

// bf16 helpers (round-to-nearest-even; inputs are finite)
__device__ inline unsigned short f2bf(float f) {
    unsigned u = __float_as_uint(f);
    return (unsigned short)((u + 0x7FFF + ((u >> 16) & 1)) >> 16);
}
// packed-pair unpack: word = (bf16 hi << 16) | bf16 lo ; lo = even feature
__device__ inline float bflo(unsigned w) { return __uint_as_float(w << 16); }
__device__ inline float bfhi(unsigned w) { return __uint_as_float(w & 0xFFFF0000u); }

// ================= phase 1: per-(bucket,block) exact counts =================
__global__ __launch_bounds__(256) void count_kernel(const int* __restrict__ dst,
                                                    int* __restrict__ cnt, int E, int nb)
{
    __shared__ int hist[1024];          // nb <= 1024
    int tid = threadIdx.x;
    for (int i = tid; i < nb; i += 256) hist[i] = 0;
    __syncthreads();
    for (int e = blockIdx.x * 256 + tid; e < E; e += NBLK * 256)
        atomicAdd(&hist[dst[e] >> BKT_SHIFT], 1);
    __syncthreads();
    for (int i = tid; i < nb; i += 256) cnt[i * NBLK + blockIdx.x] = hist[i];
}

// ================= phase 2a: per-bucket totals =================
__global__ __launch_bounds__(NBLK) void bsum_kernel(const int* __restrict__ cnt,
                                                    int* __restrict__ bsum)
{
    __shared__ int s[NBLK];
    int tid = threadIdx.x, b = blockIdx.x;
    s[tid] = cnt[b * NBLK + tid];
    __syncthreads();
    for (int off = NBLK / 2; off > 0; off >>= 1) {
        if (tid < off) s[tid] += s[tid + off];
        __syncthreads();
    }
    if (tid == 0) bsum[b] = s[0];
}

// ================= phase 2b: one-block exclusive scan of bucket totals =================
__global__ __launch_bounds__(512) void bscan_kernel(int* __restrict__ bsum, int nb,
                                                    int* __restrict__ cellstart, int nc,
                                                    int* __restrict__ rowstart, int n, int E)
{
    __shared__ int s[512];
    int tid = threadIdx.x;
    int my = (tid < nb) ? bsum[tid] : 0;
    s[tid] = my;
    __syncthreads();
    for (int off = 1; off < 512; off <<= 1) {
        int t = (tid >= off) ? s[tid - off] : 0;
        __syncthreads();
        s[tid] += t;
        __syncthreads();
    }
    if (tid < nb) bsum[tid] = s[tid] - my;      // exclusive bucket start
    if (tid == 0) { cellstart[nc] = E; rowstart[n] = E; }
}

// ================= phase 2c: per-bucket scan of its 128 cells =================
__global__ __launch_bounds__(NBLK) void cscan_kernel(const int* __restrict__ cnt,
                                                     const int* __restrict__ bsum,
                                                     int* __restrict__ cellstart)
{
    __shared__ int s[NBLK];
    int tid = threadIdx.x, b = blockIdx.x;
    int my = cnt[b * NBLK + tid];
    s[tid] = my;
    __syncthreads();
    for (int off = 1; off < NBLK; off <<= 1) {
        int t = (tid >= off) ? s[tid - off] : 0;
        __syncthreads();
        s[tid] += t;
        __syncthreads();
    }
    cellstart[b * NBLK + tid] = bsum[b] + s[tid] - my;   // exclusive
}

// ================= phase 3: append via block-private LDS cursors =================
__global__ __launch_bounds__(256) void append_kernel(
    const int* __restrict__ src, const int* __restrict__ dst,
    const int* __restrict__ cellstart, unsigned* __restrict__ pairs, int E, int nb)
{
    __shared__ int cur[1024];
    int tid = threadIdx.x;
    for (int i = tid; i < nb; i += 256) cur[i] = cellstart[i * NBLK + blockIdx.x];
    __syncthreads();
    for (int e = blockIdx.x * 256 + tid; e < E; e += NBLK * 256) {
        int d = dst[e];
        int pos = atomicAdd(&cur[d >> BKT_SHIFT], 1);     // LDS atomic
        pairs[pos] = ((unsigned)src[e] << BKT_SHIFT) | (unsigned)(d & (BKT_NODES - 1));
    }
}

// ================= phase 4: per-bucket place + rowstart + dinv =================
__global__ __launch_bounds__(256) void place_kernel(
    const int* __restrict__ cellstart, const unsigned* __restrict__ pairs,
    int* __restrict__ srcs, int* __restrict__ rowstart, float* __restrict__ dinv, int n)
{
    __shared__ int hist[BKT_NODES];
    __shared__ int ofs[BKT_NODES];
    int b = blockIdx.x, tid = threadIdx.x;
    int beg = cellstart[b * NBLK], end = cellstart[(b + 1) * NBLK];
    hist[tid] = 0;
    __syncthreads();
    for (int e = beg + tid; e < end; e += 256)
        atomicAdd(&hist[pairs[e] & (BKT_NODES - 1)], 1);
    __syncthreads();
    int my = hist[tid];
    ofs[tid] = my;
    __syncthreads();
    for (int off = 1; off < 256; off <<= 1) {
        int t = (tid >= off) ? ofs[tid - off] : 0;
        __syncthreads();
        ofs[tid] += t;
        __syncthreads();
    }
    int excl = ofs[tid] - my;
    int node = b * BKT_NODES + tid;
    if (node < n) {
        rowstart[node] = beg + excl;
        dinv[node] = rsqrtf((float)(my + 1));   // +1 self-loop
    }
    __syncthreads();
    ofs[tid] = excl;                    // reuse as LDS cursor
    __syncthreads();
    for (int e = beg + tid; e < end; e += 256) {
        unsigned p = pairs[e];
        int dl = p & (BKT_NODES - 1);
        int pos = beg + atomicAdd(&ofs[dl], 1);
        srcs[pos] = (int)(p >> BKT_SHIFT);
    }
}

// ================= xs[i][j] = bf16(dinv[i] * x[i][j]) =================
__global__ void xs_kernel(const float* __restrict__ x, const float* __restrict__ dinv,
                          unsigned short* __restrict__ xsb, int n) {
    int t = blockIdx.x * blockDim.x + threadIdx.x;
    if (t < n * (IN_F / 4)) {
        float d = dinv[t >> 3];
        float4 v = ((const float4*)x)[t];
        ushort4 o;
        o.x = f2bf(v.x * d); o.y = f2bf(v.y * d);
        o.z = f2bf(v.z * d); o.w = f2bf(v.w * d);
        ((ushort4*)xsb)[t] = o;
    }
}

// ================= fused1: quarter-wave gather -> MLP -> packed bf16 hs2 =================
// 16 nodes/block, 16 lanes per node, lane q handles packed features (2q, 2q+1).
// One wave-level gather instruction = 4 nodes = 4 cache lines in flight.
__global__ __launch_bounds__(256) void fused1_kernel(
    const int* __restrict__ rowstart, const int* __restrict__ srcs,
    const unsigned* __restrict__ xs2, const float* __restrict__ dinv,
    const float* __restrict__ b1, const float* __restrict__ W1,
    const float* __restrict__ W2, unsigned* __restrict__ hs2p, int n)
{
    __shared__ float W1s[IN_F * HID_F];    // 8 KB  [k*64+j]
    __shared__ float W2s[HID_F * OUT_F];   // 8 KB  [k*32+j]
    __shared__ float grow[16][IN_F];       // 2 KB
    __shared__ float hrow[16][HID_F];      // 4 KB
    int tid = threadIdx.x;
    for (int t = tid; t < IN_F * HID_F; t += 256) W1s[t] = W1[t];
    for (int t = tid; t < HID_F * OUT_F; t += 256) W2s[t] = W2[t];

    int nl = tid >> 4;                 // node-local 0..15
    unsigned q = tid & 15;             // feature-pair index
    int node = blockIdx.x * 16 + nl;
    bool active = node < n;
    int nodec = active ? node : 0;

    int beg = rowstart[nodec], end = active ? rowstart[nodec + 1] : beg;
    unsigned ws = active ? xs2[((unsigned)nodec << 4) + q] : 0u;   // self-loop
    float a0l = bflo(ws), a0h = bfhi(ws);
    float a1l = 0.f, a1h = 0.f, a2l = 0.f, a2h = 0.f, a3l = 0.f, a3h = 0.f;
    float a4l = 0.f, a4h = 0.f, a5l = 0.f, a5h = 0.f, a6l = 0.f, a6h = 0.f;
    float a7l = 0.f, a7h = 0.f;
    int e = beg;
    for (; e + 8 <= end; e += 8) {
        unsigned o0 = ((unsigned)srcs[e]     << 4) + q, o1 = ((unsigned)srcs[e + 1] << 4) + q;
        unsigned o2 = ((unsigned)srcs[e + 2] << 4) + q, o3 = ((unsigned)srcs[e + 3] << 4) + q;
        unsigned o4 = ((unsigned)srcs[e + 4] << 4) + q, o5 = ((unsigned)srcs[e + 5] << 4) + q;
        unsigned o6 = ((unsigned)srcs[e + 6] << 4) + q, o7 = ((unsigned)srcs[e + 7] << 4) + q;
        unsigned w0 = xs2[o0], w1 = xs2[o1], w2 = xs2[o2], w3 = xs2[o3];
        unsigned w4 = xs2[o4], w5 = xs2[o5], w6 = xs2[o6], w7 = xs2[o7];
        a0l += bflo(w0); a0h += bfhi(w0); a1l += bflo(w1); a1h += bfhi(w1);
        a2l += bflo(w2); a2h += bfhi(w2); a3l += bflo(w3); a3h += bfhi(w3);
        a4l += bflo(w4); a4h += bfhi(w4); a5l += bflo(w5); a5h += bfhi(w5);
        a6l += bflo(w6); a6h += bfhi(w6); a7l += bflo(w7); a7h += bfhi(w7);
    }
    for (; e + 4 <= end; e += 4) {
        unsigned o0 = ((unsigned)srcs[e]     << 4) + q, o1 = ((unsigned)srcs[e + 1] << 4) + q;
        unsigned o2 = ((unsigned)srcs[e + 2] << 4) + q, o3 = ((unsigned)srcs[e + 3] << 4) + q;
        unsigned w0 = xs2[o0], w1 = xs2[o1], w2 = xs2[o2], w3 = xs2[o3];
        a0l += bflo(w0); a0h += bfhi(w0); a1l += bflo(w1); a1h += bfhi(w1);
        a2l += bflo(w2); a2h += bfhi(w2); a3l += bflo(w3); a3h += bfhi(w3);
    }
    for (; e < end; ++e) {
        unsigned w0 = xs2[((unsigned)srcs[e] << 4) + q];
        a0l += bflo(w0); a0h += bfhi(w0);
    }
    float dv = dinv[nodec];
    grow[nl][2 * q]     = dv * (((a0l + a1l) + (a2l + a3l)) + ((a4l + a5l) + (a6l + a7l)));
    grow[nl][2 * q + 1] = dv * (((a0h + a1h) + (a2h + a3h)) + ((a4h + a5h) + (a6h + a7h)));
    __syncthreads();

    // ---- MLP: 16 threads/node. hidden features q, q+16, q+32, q+48 ----
    float h0 = b1[q], h1 = b1[q + 16], h2 = b1[q + 32], h3 = b1[q + 48];
    #pragma unroll
    for (int k = 0; k < IN_F; ++k) {
        float gk = grow[nl][k];                 // broadcast
        h0 += gk * W1s[k * HID_F + q];
        h1 += gk * W1s[k * HID_F + q + 16];
        h2 += gk * W1s[k * HID_F + q + 32];
        h3 += gk * W1s[k * HID_F + q + 48];
    }
    hrow[nl][q]      = fmaxf(h0, 0.f);
    hrow[nl][q + 16] = fmaxf(h1, 0.f);
    hrow[nl][q + 32] = fmaxf(h2, 0.f);
    hrow[nl][q + 48] = fmaxf(h3, 0.f);
    __syncthreads();

    // ---- W2 matvec: output features 2q, 2q+1; write packed pair ----
    float p0 = 0.f, p1 = 0.f;
    #pragma unroll
    for (int k = 0; k < HID_F; ++k) {
        float hk = hrow[nl][k];                 // broadcast
        p0 += hk * W2s[k * OUT_F + 2 * q];
        p1 += hk * W2s[k * OUT_F + 2 * q + 1];
    }
    if (active) {
        unsigned pack = (unsigned)f2bf(dv * p0) | ((unsigned)f2bf(dv * p1) << 16);
        hs2p[((unsigned)node << 4) + q] = pack;
    }
}

// ================= agg2: quarter-wave gather of packed hs2, finalize =================
__global__ __launch_bounds__(256) void agg2_kernel(
    const int* __restrict__ rowstart, const int* __restrict__ srcs,
    const unsigned* __restrict__ hs2p, const float* __restrict__ dinv,
    const float* __restrict__ b2, float* __restrict__ out, int n)
{
    int t = blockIdx.x * blockDim.x + threadIdx.x;
    int node = t >> 4;
    if (node >= n) return;
    unsigned q = t & 15;
    int beg = rowstart[node], end = rowstart[node + 1];
    unsigned ws = hs2p[((unsigned)node << 4) + q];   // self-loop
    float a0l = bflo(ws), a0h = bfhi(ws);
    float a1l = 0.f, a1h = 0.f, a2l = 0.f, a2h = 0.f, a3l = 0.f, a3h = 0.f;
    float a4l = 0.f, a4h = 0.f, a5l = 0.f, a5h = 0.f, a6l = 0.f, a6h = 0.f;
    float a7l = 0.f, a7h = 0.f;
    int e = beg;
    for (; e + 8 <= end; e += 8) {
        unsigned o0 = ((unsigned)srcs[e]     << 4) + q, o1 = ((unsigned)srcs[e + 1] << 4) + q;
        unsigned o2 = ((unsigned)srcs[e + 2] << 4) + q, o3 = ((unsigned)srcs[e + 3] << 4) + q;
        unsigned o4 = ((unsigned)srcs[e + 4] << 4) + q, o5 = ((unsigned)srcs[e + 5] << 4) + q;
        unsigned o6 = ((unsigned)srcs[e + 6] << 4) + q, o7 = ((unsigned)srcs[e + 7] << 4) + q;
        unsigned w0 = hs2p[o0], w1 = hs2p[o1], w2 = hs2p[o2], w3 = hs2p[o3];
        unsigned w4 = hs2p[o4], w5 = hs2p[o5], w6 = hs2p[o6], w7 = hs2p[o7];
        a0l += bflo(w0); a0h += bfhi(w0); a1l += bflo(w1); a1h += bfhi(w1);
        a2l += bflo(w2); a2h += bfhi(w2); a3l += bflo(w3); a3h += bfhi(w3);
        a4l += bflo(w4); a4h += bfhi(w4); a5l += bflo(w5); a5h += bfhi(w5);
        a6l += bflo(w6); a6h += bfhi(w6); a7l += bflo(w7); a7h += bfhi(w7);
    }
    for (; e + 4 <= end; e += 4) {
        unsigned o0 = ((unsigned)srcs[e]     << 4) + q, o1 = ((unsigned)srcs[e + 1] << 4) + q;
        unsigned o2 = ((unsigned)srcs[e + 2] << 4) + q, o3 = ((unsigned)srcs[e + 3] << 4) + q;
        unsigned w0 = hs2p[o0], w1 = hs2p[o1], w2 = hs2p[o2], w3 = hs2p[o3];
        a0l += bflo(w0); a0h += bfhi(w0); a1l += bflo(w1); a1h += bfhi(w1);
        a2l += bflo(w2); a2h += bfhi(w2); a3l += bflo(w3); a3h += bfhi(w3);
    }
    for (; e < end; ++e) {
        unsigned w0 = hs2p[((unsigned)srcs[e] << 4) + q];
        a0l += bflo(w0); a0h += bfhi(w0);
    }
    float dvv = dinv[node];
    float2 r;
    r.x = dvv * (((a0l + a1l) + (a2l + a3l)) + ((a4l + a5l) + (a6l + a7l))) + b2[2 * q];
    r.y = dvv * (((a0h + a1h) + (a2h + a3h)) + ((a4h + a5h) + (a6h + a7h))) + b2[2 * q + 1];
    ((float2*)out)[((size_t)node << 4) + q] = r;
}

extern "C" void kernel_launch(void* const* d_in, const int* in_sizes, int n_in,
                              void* d_out, int out_size, void* d_ws, size_t ws_size,
                              hipStream_t stream) {
    const float* x  = (const float*)d_in[0];
    const int*   ei = (const int*)  d_in[1];
    const float* W1 = (const float*)d_in[2];
    const float* b1 = (const float*)d_in[3];
    const float* W2 = (const float*)d_in[4];
    const float* b2 = (const float*)d_in[5];
    float* out = (float*)d_out;

    const int n = in_sizes[0] / IN_F;     // 100000
    const int E = in_sizes[1] / 2;        // 1600000
    const int* src = ei;
    const int* dst = ei + E;

    const int nb = (n + BKT_NODES - 1) >> BKT_SHIFT;   // 391 buckets (<=512)
    const int nc = nb * NBLK;                          // 50048 cells

    // ---- workspace layout: ~24 MB ----
    int* ip = (int*)d_ws;
    int* cnt       = ip;                 ip += nc;
    int* cellstart = ip;                 ip += nc + 1;
    int* bsum      = ip;                 ip += nb + 1;
    int* rowstart  = ip;                 ip += n + 1;
    unsigned* pairs = (unsigned*)ip;     ip += E;          // 6.4 MB
    int* srcs_srt  = ip;                 ip += E;          // 6.4 MB
    float* dinv = (float*)ip;            ip += n;
    unsigned* xs2  = (unsigned*)ip;      ip += (size_t)n * IN_F / 2;   // 6.4 MB
    unsigned* hs2p = (unsigned*)ip;                                    // 6.4 MB

    count_kernel<<<NBLK, 256, 0, stream>>>(dst, cnt, E, nb);
    bsum_kernel <<<nb, NBLK, 0, stream>>>(cnt, bsum);
    bscan_kernel<<<1, 512, 0, stream>>>(bsum, nb, cellstart, nc, rowstart, n, E);
    cscan_kernel<<<nb, NBLK, 0, stream>>>(cnt, bsum, cellstart);
    append_kernel<<<NBLK, 256, 0, stream>>>(src, dst, cellstart, pairs, E, nb);
    place_kernel<<<nb, 256, 0, stream>>>(cellstart, pairs, srcs_srt, rowstart, dinv, n);

    xs_kernel<<<((size_t)n * 8 + 255) / 256, 256, 0, stream>>>(x, dinv, (unsigned short*)xs2, n);

    fused1_kernel<<<(n + 15) / 16, 256, 0, stream>>>(rowstart, srcs_srt, xs2, dinv, b1, W1, W2, hs2p, n);
    agg2_kernel<<<((size_t)n * 16 + 255) / 256, 256, 0, stream>>>(rowstart, srcs_srt, hs2p, dinv, b2, out, n);
}

// Round 11
// 215.464 us; speedup vs baseline: 1.8680x; 1.0916x over previous
//
#include <hip/hip_runtime.h>

#define IN_F  32
#define HID_F 64
#define OUT_F 32

#define BKT_SHIFT 8            // 256 nodes per bucket
#define BKT_NODES 256
#define NBLK      512          // partition blocks — count/append edge->block map MUST match

// bf16 helpers (round-to-nearest-even; inputs are finite)
__device__ inline unsigned short f2bf(float f) {
    unsigned u = __float_as_uint(f);
    return (unsigned short)((u + 0x7FFF + ((u >> 16) & 1)) >> 16);
}
// packed-pair unpack: word = (bf16 hi << 16) | bf16 lo ; lo = even feature
__device__ inline float bflo(unsigned w) { return __uint_as_float(w << 16); }
__device__ inline float bfhi(unsigned w) { return __uint_as_float(w & 0xFFFF0000u); }

// ================= phase 1: per-(bucket,block) exact counts =================
__global__ __launch_bounds__(256) void count_kernel(const int* __restrict__ dst,
                                                    int* __restrict__ cnt, int E, int nb)
{
    __shared__ int hist[1024];          // nb <= 1024
    int tid = threadIdx.x;
    for (int i = tid; i < nb; i += 256) hist[i] = 0;
    __syncthreads();
    for (int e = blockIdx.x * 256 + tid; e < E; e += NBLK * 256)
        atomicAdd(&hist[dst[e] >> BKT_SHIFT], 1);
    __syncthreads();
    for (int i = tid; i < nb; i += 256) cnt[i * NBLK + blockIdx.x] = hist[i];
}

// ================= phase 2a: per-bucket totals (one block per bucket) =================
__global__ __launch_bounds__(NBLK) void bsum_kernel(const int* __restrict__ cnt,
                                                    int* __restrict__ bsum)
{
    __shared__ int s[NBLK];
    int tid = threadIdx.x, b = blockIdx.x;
    s[tid] = cnt[b * NBLK + tid];
    __syncthreads();
    for (int off = NBLK / 2; off > 0; off >>= 1) {
        if (tid < off) s[tid] += s[tid + off];
        __syncthreads();
    }
    if (tid == 0) bsum[b] = s[0];
}

// ================= phase 2b: one-block exclusive scan of bucket totals =================
__global__ __launch_bounds__(512) void bscan_kernel(int* __restrict__ bsum, int nb,
                                                    int* __restrict__ cellstart, int nc,
                                                    int* __restrict__ rowstart, int n, int E)
{
    __shared__ int s[512];
    int tid = threadIdx.x;
    int my = (tid < nb) ? bsum[tid] : 0;
    s[tid] = my;
    __syncthreads();
    for (int off = 1; off < 512; off <<= 1) {
        int t = (tid >= off) ? s[tid - off] : 0;
        __syncthreads();
        s[tid] += t;
        __syncthreads();
    }
    if (tid < nb) bsum[tid] = s[tid] - my;      // exclusive bucket start
    if (tid == 0) { cellstart[nc] = E; rowstart[n] = E; }
}

// ================= phase 2c: per-bucket scan of its NBLK cells =================
__global__ __launch_bounds__(NBLK) void cscan_kernel(const int* __restrict__ cnt,
                                                     const int* __restrict__ bsum,
                                                     int* __restrict__ cellstart)
{
    __shared__ int s[NBLK];
    int tid = threadIdx.x, b = blockIdx.x;
    int my = cnt[b * NBLK + tid];
    s[tid] = my;
    __syncthreads();
    for (int off = 1; off < NBLK; off <<= 1) {
        int t = (tid >= off) ? s[tid - off] : 0;
        __syncthreads();
        s[tid] += t;
        __syncthreads();
    }
    cellstart[b * NBLK + tid] = bsum[b] + s[tid] - my;   // exclusive
}

// ================= phase 3: append via block-private LDS cursors =================
__global__ __launch_bounds__(256) void append_kernel(
    const int* __restrict__ src, const int* __restrict__ dst,
    const int* __restrict__ cellstart, unsigned* __restrict__ pairs, int E, int nb)
{
    __shared__ int cur[1024];
    int tid = threadIdx.x;
    for (int i = tid; i < nb; i += 256) cur[i] = cellstart[i * NBLK + blockIdx.x];
    __syncthreads();
    for (int e = blockIdx.x * 256 + tid; e < E; e += NBLK * 256) {
        int d = dst[e];
        int pos = atomicAdd(&cur[d >> BKT_SHIFT], 1);     // LDS atomic
        pairs[pos] = ((unsigned)src[e] << BKT_SHIFT) | (unsigned)(d & (BKT_NODES - 1));
    }
}

// ================= phase 4: per-bucket place + rowstart + dinv =================
__global__ __launch_bounds__(256) void place_kernel(
    const int* __restrict__ cellstart, const unsigned* __restrict__ pairs,
    int* __restrict__ srcs, int* __restrict__ rowstart, float* __restrict__ dinv, int n)
{
    __shared__ int hist[BKT_NODES];
    __shared__ int ofs[BKT_NODES];
    int b = blockIdx.x, tid = threadIdx.x;
    int beg = cellstart[b * NBLK], end = cellstart[(b + 1) * NBLK];
    hist[tid] = 0;
    __syncthreads();
    for (int e = beg + tid; e < end; e += 256)
        atomicAdd(&hist[pairs[e] & (BKT_NODES - 1)], 1);
    __syncthreads();
    int my = hist[tid];
    ofs[tid] = my;
    __syncthreads();
    for (int off = 1; off < 256; off <<= 1) {
        int t = (tid >= off) ? ofs[tid - off] : 0;
        __syncthreads();
        ofs[tid] += t;
        __syncthreads();
    }
    int excl = ofs[tid] - my;
    int node = b * BKT_NODES + tid;
    if (node < n) {
        rowstart[node] = beg + excl;
        dinv[node] = rsqrtf((float)(my + 1));   // +1 self-loop
    }
    __syncthreads();
    ofs[tid] = excl;                    // reuse as LDS cursor
    __syncthreads();
    for (int e = beg + tid; e < end; e += 256) {
        unsigned p = pairs[e];
        int dl = p & (BKT_NODES - 1);
        int pos = beg + atomicAdd(&ofs[dl], 1);
        srcs[pos] = (int)(p >> BKT_SHIFT);
    }
}

// ================= xs[i][j] = bf16(dinv[i] * x[i][j]) =================
__global__ void xs_kernel(const float* __restrict__ x, const float* __restrict__ dinv,
                          unsigned short* __restrict__ xsb, int n) {
    int t = blockIdx.x * blockDim.x + threadIdx.x;
    if (t < n * (IN_F / 4)) {
        float d = dinv[t >> 3];
        float4 v = ((const float4*)x)[t];
        ushort4 o;
        o.x = f2bf(v.x * d); o.y = f2bf(v.y * d);
        o.z = f2bf(v.z * d); o.w = f2bf(v.w * d);
        ((ushort4*)xsb)[t] = o;
    }
}

// ================= fused1: quarter-wave gather -> MLP -> packed bf16 hs2 =================
// 16 nodes/block, 16 lanes per node, lane q handles packed features (2q, 2q+1).
// LDS tiles padded (+1) to break 4-way bank conflicts across nl groups.
__global__ __launch_bounds__(256) void fused1_kernel(
    const int* __restrict__ rowstart, const int* __restrict__ srcs,
    const unsigned* __restrict__ xs2, const float* __restrict__ dinv,
    const float* __restrict__ b1, const float* __restrict__ W1,
    const float* __restrict__ W2, unsigned* __restrict__ hs2p, int n)
{
    __shared__ float W1s[IN_F * HID_F];    // 8 KB  [k*64+j]
    __shared__ float W2s[HID_F * OUT_F];   // 8 KB  [k*32+j]
    __shared__ float grow[16][IN_F + 1];   // padded: bank = (nl+k)%32
    __shared__ float hrow[16][HID_F + 1];  // padded
    int tid = threadIdx.x;
    for (int t = tid; t < IN_F * HID_F; t += 256) W1s[t] = W1[t];
    for (int t = tid; t < HID_F * OUT_F; t += 256) W2s[t] = W2[t];

    int nl = tid >> 4;                 // node-local 0..15
    unsigned q = tid & 15;             // feature-pair index
    int node = blockIdx.x * 16 + nl;
    bool active = node < n;
    int nodec = active ? node : 0;

    int beg = rowstart[nodec], end = active ? rowstart[nodec + 1] : beg;
    unsigned ws = active ? xs2[((unsigned)nodec << 4) + q] : 0u;   // self-loop
    float a0l = bflo(ws), a0h = bfhi(ws);
    float a1l = 0.f, a1h = 0.f, a2l = 0.f, a2h = 0.f, a3l = 0.f, a3h = 0.f;
    float a4l = 0.f, a4h = 0.f, a5l = 0.f, a5h = 0.f, a6l = 0.f, a6h = 0.f;
    float a7l = 0.f, a7h = 0.f;
    int e = beg;
    for (; e + 8 <= end; e += 8) {
        unsigned o0 = ((unsigned)srcs[e]     << 4) + q, o1 = ((unsigned)srcs[e + 1] << 4) + q;
        unsigned o2 = ((unsigned)srcs[e + 2] << 4) + q, o3 = ((unsigned)srcs[e + 3] << 4) + q;
        unsigned o4 = ((unsigned)srcs[e + 4] << 4) + q, o5 = ((unsigned)srcs[e + 5] << 4) + q;
        unsigned o6 = ((unsigned)srcs[e + 6] << 4) + q, o7 = ((unsigned)srcs[e + 7] << 4) + q;
        unsigned w0 = xs2[o0], w1 = xs2[o1], w2 = xs2[o2], w3 = xs2[o3];
        unsigned w4 = xs2[o4], w5 = xs2[o5], w6 = xs2[o6], w7 = xs2[o7];
        a0l += bflo(w0); a0h += bfhi(w0); a1l += bflo(w1); a1h += bfhi(w1);
        a2l += bflo(w2); a2h += bfhi(w2); a3l += bflo(w3); a3h += bfhi(w3);
        a4l += bflo(w4); a4h += bfhi(w4); a5l += bflo(w5); a5h += bfhi(w5);
        a6l += bflo(w6); a6h += bfhi(w6); a7l += bflo(w7); a7h += bfhi(w7);
    }
    for (; e + 4 <= end; e += 4) {
        unsigned o0 = ((unsigned)srcs[e]     << 4) + q, o1 = ((unsigned)srcs[e + 1] << 4) + q;
        unsigned o2 = ((unsigned)srcs[e + 2] << 4) + q, o3 = ((unsigned)srcs[e + 3] << 4) + q;
        unsigned w0 = xs2[o0], w1 = xs2[o1], w2 = xs2[o2], w3 = xs2[o3];
        a0l += bflo(w0); a0h += bfhi(w0); a1l += bflo(w1); a1h += bfhi(w1);
        a2l += bflo(w2); a2h += bfhi(w2); a3l += bflo(w3); a3h += bfhi(w3);
    }
    for (; e < end; ++e) {
        unsigned w0 = xs2[((unsigned)srcs[e] << 4) + q];
        a0l += bflo(w0); a0h += bfhi(w0);
    }
    float dv = dinv[nodec];
    grow[nl][2 * q]     = dv * (((a0l + a1l) + (a2l + a3l)) + ((a4l + a5l) + (a6l + a7l)));
    grow[nl][2 * q + 1] = dv * (((a0h + a1h) + (a2h + a3h)) + ((a4h + a5h) + (a6h + a7h)));
    __syncthreads();

    // ---- MLP: 16 threads/node. hidden features q, q+16, q+32, q+48 ----
    float h0 = b1[q], h1 = b1[q + 16], h2 = b1[q + 32], h3 = b1[q + 48];
    #pragma unroll
    for (int k = 0; k < IN_F; ++k) {
        float gk = grow[nl][k];                 // 4 addrs/wave, 4 distinct banks
        h0 += gk * W1s[k * HID_F + q];
        h1 += gk * W1s[k * HID_F + q + 16];
        h2 += gk * W1s[k * HID_F + q + 32];
        h3 += gk * W1s[k * HID_F + q + 48];
    }
    hrow[nl][q]      = fmaxf(h0, 0.f);
    hrow[nl][q + 16] = fmaxf(h1, 0.f);
    hrow[nl][q + 32] = fmaxf(h2, 0.f);
    hrow[nl][q + 48] = fmaxf(h3, 0.f);
    __syncthreads();

    // ---- W2 matvec: output features 2q, 2q+1; write packed pair ----
    float p0 = 0.f, p1 = 0.f;
    #pragma unroll
    for (int k = 0; k < HID_F; ++k) {
        float hk = hrow[nl][k];                 // 4 addrs/wave, 4 distinct banks
        p0 += hk * W2s[k * OUT_F + 2 * q];
        p1 += hk * W2s[k * OUT_F + 2 * q + 1];
    }
    if (active) {
        unsigned pack = (unsigned)f2bf(dv * p0) | ((unsigned)f2bf(dv * p1) << 16);
        hs2p[((unsigned)node << 4) + q] = pack;
    }
}

// ================= agg2: quarter-wave gather of packed hs2, finalize =================
__global__ __launch_bounds__(256) void agg2_kernel(
    const int* __restrict__ rowstart, const int* __restrict__ srcs,
    const unsigned* __restrict__ hs2p, const float* __restrict__ dinv,
    const float* __restrict__ b2, float* __restrict__ out, int n)
{
    int t = blockIdx.x * blockDim.x + threadIdx.x;
    int node = t >> 4;
    if (node >= n) return;
    unsigned q = t & 15;
    int beg = rowstart[node], end = rowstart[node + 1];
    unsigned ws = hs2p[((unsigned)node << 4) + q];   // self-loop
    float a0l = bflo(ws), a0h = bfhi(ws);
    float a1l = 0.f, a1h = 0.f, a2l = 0.f, a2h = 0.f, a3l = 0.f, a3h = 0.f;
    float a4l = 0.f, a4h = 0.f, a5l = 0.f, a5h = 0.f, a6l = 0.f, a6h = 0.f;
    float a7l = 0.f, a7h = 0.f;
    int e = beg;
    for (; e + 8 <= end; e += 8) {
        unsigned o0 = ((unsigned)srcs[e]     << 4) + q, o1 = ((unsigned)srcs[e + 1] << 4) + q;
        unsigned o2 = ((unsigned)srcs[e + 2] << 4) + q, o3 = ((unsigned)srcs[e + 3] << 4) + q;
        unsigned o4 = ((unsigned)srcs[e + 4] << 4) + q, o5 = ((unsigned)srcs[e + 5] << 4) + q;
        unsigned o6 = ((unsigned)srcs[e + 6] << 4) + q, o7 = ((unsigned)srcs[e + 7] << 4) + q;
        unsigned w0 = hs2p[o0], w1 = hs2p[o1], w2 = hs2p[o2], w3 = hs2p[o3];
        unsigned w4 = hs2p[o4], w5 = hs2p[o5], w6 = hs2p[o6], w7 = hs2p[o7];
        a0l += bflo(w0); a0h += bfhi(w0); a1l += bflo(w1); a1h += bfhi(w1);
        a2l += bflo(w2); a2h += bfhi(w2); a3l += bflo(w3); a3h += bfhi(w3);
        a4l += bflo(w4); a4h += bfhi(w4); a5l += bflo(w5); a5h += bfhi(w5);
        a6l += bflo(w6); a6h += bfhi(w6); a7l += bflo(w7); a7h += bfhi(w7);
    }
    for (; e + 4 <= end; e += 4) {
        unsigned o0 = ((unsigned)srcs[e]     << 4) + q, o1 = ((unsigned)srcs[e + 1] << 4) + q;
        unsigned o2 = ((unsigned)srcs[e + 2] << 4) + q, o3 = ((unsigned)srcs[e + 3] << 4) + q;
        unsigned w0 = hs2p[o0], w1 = hs2p[o1], w2 = hs2p[o2], w3 = hs2p[o3];
        a0l += bflo(w0); a0h += bfhi(w0); a1l += bflo(w1); a1h += bfhi(w1);
        a2l += bflo(w2); a2h += bfhi(w2); a3l += bflo(w3); a3h += bfhi(w3);
    }
    for (; e < end; ++e) {
        unsigned w0 = hs2p[((unsigned)srcs[e] << 4) + q];
        a0l += bflo(w0); a0h += bfhi(w0);
    }
    float dvv = dinv[node];
    float2 r;
    r.x = dvv * (((a0l + a1l) + (a2l + a3l)) + ((a4l + a5l) + (a6l + a7l))) + b2[2 * q];
    r.y = dvv * (((a0h + a1h) + (a2h + a3h)) + ((a4h + a5h) + (a6h + a7h))) + b2[2 * q + 1];
    ((float2*)out)[((size_t)node << 4) + q] = r;
}

extern "C" void kernel_launch(void* const* d_in, const int* in_sizes, int n_in,
                              void* d_out, int out_size, void* d_ws, size_t ws_size,
                              hipStream_t stream) {
    const float* x  = (const float*)d_in[0];
    const int*   ei = (const int*)  d_in[1];
    const float* W1 = (const float*)d_in[2];
    const float* b1 = (const float*)d_in[3];
    const float* W2 = (const float*)d_in[4];
    const float* b2 = (const float*)d_in[5];
    float* out = (float*)d_out;

    const int n = in_sizes[0] / IN_F;     // 100000
    const int E = in_sizes[1] / 2;        // 1600000
    const int* src = ei;
    const int* dst = ei + E;

    const int nb = (n + BKT_NODES - 1) >> BKT_SHIFT;   // 391 buckets (<=512)
    const int nc = nb * NBLK;                          // 200192 cells

    // ---- workspace layout: ~27 MB ----
    int* ip = (int*)d_ws;
    int* cnt       = ip;                 ip += nc;         // 0.8 MB
    int* cellstart = ip;                 ip += nc + 1;     // 0.8 MB
    int* bsum      = ip;                 ip += nb + 1;
    int* rowstart  = ip;                 ip += n + 1;
    unsigned* pairs = (unsigned*)ip;     ip += E;          // 6.4 MB
    int* srcs_srt  = ip;                 ip += E;          // 6.4 MB
    float* dinv = (float*)ip;            ip += n;
    unsigned* xs2  = (unsigned*)ip;      ip += (size_t)n * IN_F / 2;   // 6.4 MB
    unsigned* hs2p = (unsigned*)ip;                                    // 6.4 MB

    count_kernel<<<NBLK, 256, 0, stream>>>(dst, cnt, E, nb);
    bsum_kernel <<<nb, NBLK, 0, stream>>>(cnt, bsum);
    bscan_kernel<<<1, 512, 0, stream>>>(bsum, nb, cellstart, nc, rowstart, n, E);
    cscan_kernel<<<nb, NBLK, 0, stream>>>(cnt, bsum, cellstart);
    append_kernel<<<NBLK, 256, 0, stream>>>(src, dst, cellstart, pairs, E, nb);
    place_kernel<<<nb, 256, 0, stream>>>(cellstart, pairs, srcs_srt, rowstart, dinv, n);

    xs_kernel<<<((size_t)n * 8 + 255) / 256, 256, 0, stream>>>(x, dinv, (unsigned short*)xs2, n);

    fused1_kernel<<<(n + 15) / 16, 256, 0, stream>>>(rowstart, srcs_srt, xs2, dinv, b1, W1, W2, hs2p, n);
    agg2_kernel<<<((size_t)n * 16 + 255) / 256, 256, 0, stream>>>(rowstart, srcs_srt, hs2p, dinv, b2, out, n);
}